// Round 14
// baseline (594.037 us; speedup 1.0000x reference)
//
#include <hip/hip_runtime.h>

typedef unsigned short u16;
typedef unsigned int   u32;
typedef unsigned long long u64;

#define B_DIM 16
#define D_DIM 768
#define T_DIM 4096
#define K_DIM 1024
#define NROW  (B_DIM * T_DIM)   // 65536 rows (b*T + t)
#define NPART (16 * 12 * 64)    // prep_z grid = 12288

// out layout (float32): out[0]=loss; out[1 + (b*D+d)*T + t]=z_q_st; out[IDX_OFF + b*T + t]=idx
#define IDX_OFF (1 + (size_t)B_DIM * D_DIM * T_DIM)

#define MARGIN_SI 185           // 7e-4 in 2^-18 units (2G numpy slack + ~16 sigma of eh-only score error)
#define SC_SCALE 3.814697265625e-06f   // 2^-18
#define INV_N 1.9868215e-8f            // 1/(16*768*4096)

#define LIST2_CAP 4096
#define ZPAD 772

// ---- scratch carved out of d_out's z_q region (overwritten by vq_out at the end) ----
#define ZH_OFF    ((size_t)64)                                  // bf16 z, [row][768], pre-swizzled (96 MB)
#define EH_OFF    (ZH_OFF + (size_t)NROW * D_DIM * 2)           // bf16 e hi
#define EL_OFF    (EH_OFF + (size_t)K_DIM * D_DIM * 2)          // (unused; layout stability)
#define EE_OFF    (EL_OFF + (size_t)K_DIM * D_DIM * 2)          // fp32 ||e_k||^2
#define CNT_OFF   (EE_OFF + (size_t)K_DIM * 4)                  // int cnt[0]=list1, cnt[1]=list2
#define LIST_OFF  (CNT_OFF + 64)                                // int list1 rows (<=65536)
#define LIST2_OFF (LIST_OFF + (size_t)NROW * 4)                 // int list2 rows (cap 4096)
#define CAND_OFF  (LIST2_OFF + (size_t)LIST2_CAP * 4)           // int2 (k2,k3) per row
#define ZPART_OFF (CAND_OFF + (size_t)NROW * 8)                 // float zpart[12288]
#define KEY_OFF   (ZPART_OFF + (size_t)NPART * 4)               // u64 keys (cap 4096)

static __device__ inline u16 f2bf(float x) {
    u32 u = __float_as_uint(x);
    u += 0x7fffu + ((u >> 16) & 1u);
    return (u16)(u >> 16);
}

typedef __attribute__((ext_vector_type(8))) short short8v;
typedef __attribute__((ext_vector_type(4))) float float4v;

static __device__ inline void gload16(const u16* g, u16* l) {
    __builtin_amdgcn_global_load_lds(
        (const __attribute__((address_space(1))) u32*)g,
        (__attribute__((address_space(3))) u32*)(uintptr_t)(void*)l,
        16, 0, 0);
}

#define LEXLT(av, ak, bv, bk) ((av) < (bv) || ((av) == (bv) && (ak) < (bk)))

// branchless sorted-insert of x into k1<=k2<=k3 (keep 3 smallest), 5 ops.
static __device__ inline void insk(int x, int& k1, int& k2, int& k3) {
    int t = max(k1, x);
    k1 = min(k1, x);
    int u = max(k2, t);
    k2 = min(k2, t);
    k3 = min(k3, u);
}

// ---------------- fused prep: ||e||^2 + e hi split (swizzled) + zero counters/loss + init keys ----------------
__global__ __launch_bounds__(256) void vq_prep(const float* __restrict__ e,
                                               u16* __restrict__ eh,
                                               float* __restrict__ ee, int* __restrict__ cnt,
                                               u64* __restrict__ keys,
                                               float* __restrict__ out)
{
    const int tid = threadIdx.x, bid = blockIdx.x;
    if (bid == 0 && tid == 0) { cnt[0] = 0; cnt[1] = 0; out[0] = 0.0f; }
    int lin = bid * 256 + tid;
    if (lin < LIST2_CAP) keys[lin] = ~0ull;
    if (bid < 4) {
        int k = bid * 256 + tid;
        const float* er = e + (size_t)k * D_DIM;
        double s = 0.0;
        for (int d = 0; d < D_DIM; ++d) { double ed = (double)er[d]; s = fma(ed, ed, s); }
        ee[k] = (float)s;
    }
    for (int t = lin; t < K_DIM * 96; t += 64 * 256) {
        int k = t / 96;
        int ch = t - k * 96;              // 8-elem chunk id
        const float* src = e + (size_t)k * D_DIM + ch * 8;
        u16 h[8];
        #pragma unroll
        for (int q = 0; q < 8; ++q) h[q] = f2bf(src[q]);
        int dst = (ch >> 3) * 64 + (((ch & 7) ^ (k & 7)) << 3);
        *(uint4*)(eh + (size_t)k * D_DIM + dst) = *(const uint4*)h;
    }
}

// ---------------- prep: z transpose -> bf16 zh (swizzled) + optional fp32 zt32 + z^2 partials ----------------
__global__ __launch_bounds__(256) void vq_prep_z(const float* __restrict__ z, u16* __restrict__ zh,
                                                 float* __restrict__ zt32, float* __restrict__ zpart)
{
    __shared__ u16 tmp[64][72];
    __shared__ float tmp32[64][66];
    __shared__ double lredd[4];
    int bi = blockIdx.x;
    int dg = bi % 12;
    int tg = (bi / 12) % 64;
    int b  = bi / (12 * 64);
    int tid = threadIdx.x;
    int tl4 = (tid & 15) * 4;
    int dl  = tid >> 4;
    double s = 0.0;
    #pragma unroll
    for (int p = 0; p < 4; ++p) {
        int d = dg * 64 + p * 16 + dl;
        const float* src = z + ((size_t)b * D_DIM + d) * T_DIM + tg * 64 + tl4;
        float4 v = *(const float4*)src;
        tmp[tl4 + 0][p * 16 + dl] = f2bf(v.x);
        tmp[tl4 + 1][p * 16 + dl] = f2bf(v.y);
        tmp[tl4 + 2][p * 16 + dl] = f2bf(v.z);
        tmp[tl4 + 3][p * 16 + dl] = f2bf(v.w);
        tmp32[tl4 + 0][p * 16 + dl] = v.x;
        tmp32[tl4 + 1][p * 16 + dl] = v.y;
        tmp32[tl4 + 2][p * 16 + dl] = v.z;
        tmp32[tl4 + 3][p * 16 + dl] = v.w;
        s = fma((double)v.x, (double)v.x, s);
        s = fma((double)v.y, (double)v.y, s);
        s = fma((double)v.z, (double)v.z, s);
        s = fma((double)v.w, (double)v.w, s);
    }
    #pragma unroll
    for (int m = 1; m < 64; m <<= 1) s += __shfl_xor(s, m);
    if ((tid & 63) == 0) lredd[tid >> 6] = s;
    __syncthreads();
    if (tid == 0) zpart[bi] = (float)(lredd[0] + lredd[1] + lredd[2] + lredd[3]);
    #pragma unroll
    for (int w = 0; w < 2; ++w) {
        int lin = tid * 2 + w;            // 0..511 = 64 rows x 8 chunks
        int tl  = lin >> 3;
        int c   = lin & 7;
        size_t row_g = (size_t)b * T_DIM + tg * 64 + tl;
        int cs = c ^ ((int)row_g & 7);
        uint4 val = *(const uint4*)&tmp[tl][c * 8];
        *(uint4*)(zh + row_g * D_DIM + dg * 64 + cs * 8) = val;
    }
    if (zt32) {
        #pragma unroll
        for (int w = 0; w < 4; ++w) {
            int lin = tid * 4 + w;        // 0..1023 = 64 rows x 16 float4
            int tl = lin >> 4;
            int cq = lin & 15;
            size_t row_g = (size_t)b * T_DIM + tg * 64 + tl;
            float4 v;
            v.x = tmp32[tl][cq * 4 + 0];
            v.y = tmp32[tl][cq * 4 + 1];
            v.z = tmp32[tl][cq * 4 + 2];
            v.w = tmp32[tl][cq * 4 + 3];
            *(float4*)(zt32 + row_g * D_DIM + dg * 64 + cq * 4) = v;
        }
    }
}

// ---------------- reduce z^2 partials into loss ----------------
__global__ __launch_bounds__(256) void vq_loss(const float* __restrict__ zpart, float* __restrict__ out)
{
    __shared__ double r[4];
    double s = 0.0;
    for (int i = threadIdx.x; i < NPART; i += 256) s += (double)zpart[i];
    #pragma unroll
    for (int m = 1; m < 64; m <<= 1) s += __shfl_xor(s, m);
    if ((threadIdx.x & 63) == 0) r[threadIdx.x >> 6] = s;
    __syncthreads();
    if (threadIdx.x == 0) atomicAdd(out, (float)((r[0] + r[1] + r[2] + r[3]) * (double)INV_N));
}

// ---------------- main: bf16 MFMA scores (eh only), packed-key top-3 + routing + sc-sum ----------------
// LDS 40448 B <= 40960 -> 4 blocks/CU; VGPR 84 <= 128 cap for 4 waves/SIMD.
__global__ __launch_bounds__(256, 4) void vq_main_mfma(const u16* __restrict__ zh,
                                                       const u16* __restrict__ eh,
                                                       const float* __restrict__ ee_g,
                                                       float* __restrict__ out,
                                                       int* __restrict__ cnt,
                                                       int* __restrict__ list1,
                                                       int* __restrict__ list2,
                                                       int2* __restrict__ cand)
{
    __shared__ u16 zt[128 * 64];
    __shared__ u16 eht[128 * 64];
    __shared__ float eeS[K_DIM];              // ||e||^2 * 2^18
    __shared__ int pk3[128][2][3];
    __shared__ float scred[2];

    const int tid  = threadIdx.x;
    const int wid  = tid >> 6;
    const int lane = tid & 63;
    const int wm = wid >> 1, wn = wid & 1;
    const int l15 = lane & 15, l4 = lane >> 4;
    const int row_block = blockIdx.x * 128;

    for (int i = tid; i < K_DIM; i += 256) eeS[i] = ee_g[i] * 262144.0f;

    int kq1[16], kq2[16], kq3[16];
    #pragma unroll
    for (int i = 0; i < 16; ++i) { kq1[i] = 0x7fffffff; kq2[i] = 0x7fffffff; kq3[i] = 0x7fffffff; }

    const int r8 = lane >> 3;
    const int ch = lane & 7;

    for (int n0 = 0; n0 < 8; ++n0) {
        float4v acc[4][4];
        #pragma unroll
        for (int mf = 0; mf < 4; ++mf)
            #pragma unroll
            for (int nf = 0; nf < 4; ++nf) acc[mf][nf] = (float4v)0.0f;

        for (int d0i = 0; d0i < 12; ++d0i) {
            const int d0 = d0i * 64;
            __syncthreads();
            #pragma unroll
            for (int q = 0; q < 4; ++q) {
                int lr = wid * 32 + q * 8;
                gload16(zh + (size_t)(row_block + lr + r8) * D_DIM + d0 + ch * 8, &zt[lr * 64]);
            }
            #pragma unroll
            for (int q = 0; q < 4; ++q) {
                int lr = wid * 32 + q * 8;
                gload16(eh + (size_t)(n0 * 128 + lr + r8) * D_DIM + d0 + ch * 8, &eht[lr * 64]);
            }
            __syncthreads();

            #pragma unroll
            for (int s = 0; s < 2; ++s) {
                short8v a[4], bh4[4];
                #pragma unroll
                for (int mf = 0; mf < 4; ++mf) {
                    int r = wm * 64 + mf * 16 + l15;
                    int cs = (s * 4 + l4) ^ (r & 7);
                    a[mf] = *(const short8v*)&zt[r * 64 + cs * 8];
                }
                #pragma unroll
                for (int nf = 0; nf < 4; ++nf) {
                    int r = wn * 64 + nf * 16 + l15;
                    int cs = (s * 4 + l4) ^ (r & 7);
                    bh4[nf] = *(const short8v*)&eht[r * 64 + cs * 8];
                }
                #pragma unroll
                for (int mf = 0; mf < 4; ++mf)
                    #pragma unroll
                    for (int nf = 0; nf < 4; ++nf)
                        acc[mf][nf] = __builtin_amdgcn_mfma_f32_16x16x32_bf16(a[mf], bh4[nf], acc[mf][nf], 0, 0, 0);
            }
        }

        // fold: key = ((int)((ee - 2*acc) * 2^18) << 10) + code ; keep 3 smallest per slot
        #pragma unroll
        for (int nf = 0; nf < 4; ++nf) {
            int kg = n0 * 128 + wn * 64 + nf * 16 + l15;
            float eev = eeS[kg];
            #pragma unroll
            for (int mf = 0; mf < 4; ++mf)
                #pragma unroll
                for (int rr = 0; rr < 4; ++rr) {
                    float sc2 = fmaf(acc[mf][nf][rr], -524288.0f, eev);   // sc * 2^18
                    int si = (int)sc2;
                    int key = (si << 10) + kg;
                    const int slot = mf * 4 + rr;
                    insk(key, kq1[slot], kq2[slot], kq3[slot]);
                }
        }
    }

    // merge across the 16 lanes sharing l4 (masks 1,2,4,8)
    #pragma unroll
    for (int m = 1; m < 16; m <<= 1) {
        #pragma unroll
        for (int i = 0; i < 16; ++i) {
            int o1 = __shfl_xor(kq1[i], m);
            int o2 = __shfl_xor(kq2[i], m);
            int o3 = __shfl_xor(kq3[i], m);
            insk(o1, kq1[i], kq2[i], kq3[i]);
            insk(o2, kq1[i], kq2[i], kq3[i]);
            insk(o3, kq1[i], kq2[i], kq3[i]);
        }
    }

    // publish per-half top-3, merge halves, route
    if (l15 == 0) {
        #pragma unroll
        for (int mf = 0; mf < 4; ++mf)
            #pragma unroll
            for (int rr = 0; rr < 4; ++rr) {
                int slot = mf * 4 + rr;
                int rl = wm * 64 + mf * 16 + l4 * 4 + rr;   // 0..127
                pk3[rl][wn][0] = kq1[slot];
                pk3[rl][wn][1] = kq2[slot];
                pk3[rl][wn][2] = kq3[slot];
            }
    }
    __syncthreads();
    float scf = 0.0f;
    if (tid < 128) {
        int a1 = pk3[tid][0][0], a2 = pk3[tid][0][1], a3 = pk3[tid][0][2];
        insk(pk3[tid][1][0], a1, a2, a3);
        insk(pk3[tid][1][1], a1, a2, a3);
        insk(pk3[tid][1][2], a1, a2, a3);
        int s1 = a1 >> 10, s2 = a2 >> 10, s3 = a3 >> 10;   // arithmetic shift -> si
        int row = row_block + tid;
        out[IDX_OFF + row] = (float)(a1 & 1023);
        scf = (float)s1 * SC_SCALE;
        if (s3 - s1 < MARGIN_SI) {
            int p = atomicAdd(&cnt[1], 1);
            if (p < LIST2_CAP) list2[p] = row;
        } else if (s2 - s1 < MARGIN_SI) {
            int p = atomicAdd(&cnt[0], 1);
            list1[p] = row;
            cand[row] = make_int2(a2 & 1023, a3 & 1023);
        }
    }
    // sc-sum for loss (waves 2,3 contribute 0)
    #pragma unroll
    for (int m = 1; m < 64; m <<= 1) scf += __shfl_xor(scf, m);
    if (lane == 0 && wid < 2) scred[wid] = scf;
    __syncthreads();
    if (tid == 0) atomicAdd(out, (scred[0] + scred[1]) * INV_N);
}

// ---------------- fixup-lite: exact numpy-fp32 rescore of {k1,k2,k3} per flagged row ----------------
__global__ __launch_bounds__(256) void vq_fixup_lite(const float* __restrict__ z,
                                                     const float* __restrict__ zt32,
                                                     const float* __restrict__ e,
                                                     const float* __restrict__ ee,
                                                     float* __restrict__ out,
                                                     const int* __restrict__ list1,
                                                     const int* __restrict__ cnt,
                                                     const int2* __restrict__ cand)
{
    __shared__ float zr[16][776];
    __shared__ double afl[16];
    __shared__ int rowsL[16];
    __shared__ int candL[16][3];
    __shared__ float dqL[16][3];

    const int tid = threadIdx.x;
    int total = cnt[0];
    if (total > NROW) total = NROW;
    int ngroups = (total + 15) >> 4;

    for (int g = blockIdx.x; g < ngroups; g += gridDim.x) {
        int nr = total - g * 16; if (nr > 16) nr = 16;
        __syncthreads();
        if (tid < 16) {
            int row = list1[g * 16 + ((tid < nr) ? tid : 0)];
            rowsL[tid] = row;
            candL[tid][0] = (int)out[IDX_OFF + row];
            int2 cc = cand[row];
            candL[tid][1] = cc.x;
            candL[tid][2] = cc.y;
        }
        __syncthreads();
        if (zt32) {
            #pragma unroll
            for (int j = 0; j < 12; ++j) {
                int lin = tid + 256 * j;          // 0..3071 = 16 rows x 192 float4
                int r = lin / 192;
                int dq = (lin - r * 192) * 4;
                *(float4*)&zr[r][dq] = *(const float4*)(zt32 + (size_t)rowsL[r] * D_DIM + dq);
            }
        } else {
            int r = tid >> 4, sub = tid & 15;
            int row = rowsL[r];
            int b = row >> 12, t = row & 4095;
            const float* zp = z + (size_t)b * D_DIM * T_DIM + t;
            #pragma unroll 4
            for (int j = 0; j < 48; ++j) {
                int d = sub + 16 * j;
                zr[r][d] = zp[(size_t)d * T_DIM];
            }
        }
        __syncthreads();
        {   // A = fl32(fp64 sum z^2) (any assoc: grid-shift invariance)
            int r = tid >> 4, sub = tid & 15;
            double s = 0.0;
            for (int d = sub; d < D_DIM; d += 16) { double zd = (double)zr[r][d]; s = fma(zd, zd, s); }
            #pragma unroll
            for (int m = 1; m < 16; m <<= 1) s += __shfl_xor(s, m);
            if (sub == 0) afl[r] = s;
        }
        __syncthreads();
        if (tid < 96) {
            int c = tid >> 5;             // candidate 0..2
            int p = (tid >> 4) & 1;       // panel 0/1
            int r = tid & 15;             // row slot
            int kk = candL[r][c];
            const float* ep = e + (size_t)kk * D_DIM + p * 384;
            const float* zp = &zr[r][p * 384];
            float a0 = 0.0f;
            #pragma unroll 8
            for (int j = 0; j < 96; ++j) {
                float4 ev = *(const float4*)(ep + j * 4);
                float4 zv = *(const float4*)(zp + j * 4);
                a0 = fmaf(zv.x, ev.x, a0);
                a0 = fmaf(zv.y, ev.y, a0);
                a0 = fmaf(zv.z, ev.z, a0);
                a0 = fmaf(zv.w, ev.w, a0);
            }
            float other = __shfl_xor(a0, 16);
            if (p == 0) {
                float M  = a0 + other;                 // fl(S1+S2), OpenBLAS 384-panel split
                float t1 = (float)afl[r] + ee[kk];     // fl(A+E)
                dqL[r][c] = t1 - 2.0f * M;             // fl(fl(A+E) - 2M)
            }
        }
        __syncthreads();
        if (tid < nr) {
            float dv = dqL[tid][0]; int dk = candL[tid][0];
            #pragma unroll
            for (int c = 1; c < 3; ++c) {
                float v = dqL[tid][c]; int k2 = candL[tid][c];
                if (LEXLT(v, k2, dv, dk)) { dv = v; dk = k2; }
            }
            out[IDX_OFF + rowsL[tid]] = (float)dk;
        }
    }
}

// ---------------- fixup-full: exact 1024-code scan, sliced 8-ways across blocks ----------------
// thread map: p = t&1 (panel), r = (t>>1)&7 (row), c = t>>4 (code lane 0..15)
// slice s covers codes [s*128, s*128+128) as 8 groups of 16; e read direct from global (L2, broadcast)
__global__ __launch_bounds__(256) void vq_fixup_full(const float* __restrict__ z,
                                                     const float* __restrict__ zt32,
                                                     const float* __restrict__ e,
                                                     const float* __restrict__ ee,
                                                     const int* __restrict__ list2,
                                                     const int* __restrict__ cnt,
                                                     u64* __restrict__ keys)
{
    __shared__ float zr[8][ZPAD];
    __shared__ double afl[8];
    __shared__ int rowsL[8];
    __shared__ float dvL[8][17];
    __shared__ int   dkL[8][17];

    const int tid = threadIdx.x;
    const int p = tid & 1;
    const int r = (tid >> 1) & 7;
    const int c = tid >> 4;
    int total = cnt[1];
    if (total > LIST2_CAP) total = LIST2_CAP;
    if (total == 0) return;
    int nchunk = (total + 7) >> 3;
    int ntasks = nchunk * 8;

    for (int task = blockIdx.x; task < ntasks; task += gridDim.x) {
        int cj = task >> 3;
        int slice = task & 7;
        int nr = total - cj * 8; if (nr > 8) nr = 8;
        __syncthreads();
        if (tid < 8) rowsL[tid] = list2[cj * 8 + ((tid < nr) ? tid : 0)];
        __syncthreads();
        if (zt32) {
            #pragma unroll
            for (int j = 0; j < 6; ++j) {
                int lin = tid + 256 * j;          // 0..1535 = 8 rows x 192 float4
                int r2 = lin / 192;
                int dq = (lin - r2 * 192) * 4;
                *(float4*)&zr[r2][dq] = *(const float4*)(zt32 + (size_t)rowsL[r2] * D_DIM + dq);
            }
        } else {
            int rs = tid >> 5, sub = tid & 31;
            int row = rowsL[rs];
            int b = row >> 12, t = row & 4095;
            const float* zp = z + (size_t)b * D_DIM * T_DIM + t;
            #pragma unroll 4
            for (int j = 0; j < 24; ++j) {
                int d = sub + 32 * j;
                zr[rs][d] = zp[(size_t)d * T_DIM];
            }
        }
        __syncthreads();
        {   // A = fl32(fp64 sum z^2)
            int rs = tid >> 5, sub = tid & 31;
            double s = 0.0;
            for (int d = sub; d < D_DIM; d += 32) { double zd = (double)zr[rs][d]; s = fma(zd, zd, s); }
            #pragma unroll
            for (int m = 1; m < 32; m <<= 1) s += __shfl_xor(s, m);
            if (sub == 0) afl[rs] = s;
        }
        __syncthreads();
        const float Af = (float)afl[r];
        const float* zp = &zr[r][p * 384];

        float bd = 3.4e38f;
        int   bkk = 0x7fffffff;

        #pragma unroll 2
        for (int g2 = 0; g2 < 8; ++g2) {
            int code = slice * 128 + g2 * 16 + c;
            const float* ep = e + (size_t)code * D_DIM + p * 384;
            float a0 = 0.0f;
            #pragma unroll 8
            for (int j = 0; j < 96; ++j) {
                float4 zv = *(const float4*)(zp + j * 4);
                float4 ev = *(const float4*)(ep + j * 4);
                a0 = fmaf(zv.x, ev.x, a0);
                a0 = fmaf(zv.y, ev.y, a0);
                a0 = fmaf(zv.z, ev.z, a0);
                a0 = fmaf(zv.w, ev.w, a0);
            }
            float other = __shfl_xor(a0, 1);
            if (p == 0) {
                float M  = a0 + other;            // fl(S1+S2), OpenBLAS 384-panel split
                float t1 = Af + ee[code];         // fl(A+E)
                float dq = t1 - 2.0f * M;         // fl(fl(A+E) - 2M)
                if (LEXLT(dq, code, bd, bkk)) { bd = dq; bkk = code; }
            }
        }

        if (p == 0) { dvL[r][c] = bd; dkL[r][c] = bkk; }
        __syncthreads();
        if (tid < 8 && tid < nr) {
            float v = dvL[tid][0]; int kk = dkL[tid][0];
            #pragma unroll
            for (int i = 1; i < 16; ++i) {
                float v2 = dvL[tid][i]; int k2 = dkL[tid][i];
                if (LEXLT(v2, k2, v, kk)) { v = v2; kk = k2; }
            }
            u64 key = ((u64)__float_as_uint(v) << 32) | (u64)(u32)kk;
            atomicMin(&keys[cj * 8 + tid], key);
        }
        __syncthreads();
    }
}

// ---------------- convert full-scan keys -> idx ----------------
__global__ __launch_bounds__(256) void vq_conv(float* __restrict__ out,
                                               const int* __restrict__ list2,
                                               const int* __restrict__ cnt,
                                               const u64* __restrict__ keys)
{
    int total = cnt[1];
    if (total > LIST2_CAP) total = LIST2_CAP;
    for (int i = threadIdx.x; i < total; i += 256) {
        out[IDX_OFF + list2[i]] = (float)(u32)(keys[i] & 0xffffffffu);
    }
}

// ---------------- gather z_q -> transposed write (loss already accumulated) ----------------
__global__ __launch_bounds__(256) void vq_out(const float* __restrict__ e,
                                              float* __restrict__ out)
{
    const int tid  = threadIdx.x;
    const int mIdx = blockIdx.x;
    const int b    = mIdx >> 5;
    const int t0   = (mIdx & 31) * 128;

    const int t  = tid & 127;
    const int ds = tid >> 7;
    const int gt = t0 + t;
    const int k  = (int)out[IDX_OFF + (size_t)b * T_DIM + gt];
    const float* er = e + (size_t)k * D_DIM;
    for (int d0 = ds * 4; d0 < D_DIM; d0 += 8) {
        float4 v = *(const float4*)(er + d0);
        float vv[4];
        *(float4*)vv = v;
        #pragma unroll
        for (int j = 0; j < 4; ++j) {
            size_t o = (size_t)(b * D_DIM + d0 + j) * T_DIM + gt;
            out[1 + o] = vv[j];
        }
    }
}

extern "C" void kernel_launch(void* const* d_in, const int* in_sizes, int n_in,
                              void* d_out, int out_size, void* d_ws, size_t ws_size,
                              hipStream_t stream) {
    const float* z = (const float*)d_in[0];
    const float* e = (const float*)d_in[1];
    float* out = (float*)d_out;
    char* ob = (char*)d_out;
    u16*   zh    = (u16*)(ob + ZH_OFF);
    u16*   eh    = (u16*)(ob + EH_OFF);
    float* eeg   = (float*)(ob + EE_OFF);
    int*   cntp  = (int*)(ob + CNT_OFF);
    int*   list1 = (int*)(ob + LIST_OFF);
    int*   list2 = (int*)(ob + LIST2_OFF);
    int2*  candp = (int2*)(ob + CAND_OFF);
    float* zpart = (float*)(ob + ZPART_OFF);
    u64*   keys  = (u64*)(ob + KEY_OFF);
    // fp32 transposed z lives in d_ws when it fits; else fall back to strided gathers
    float* zt32 = (ws_size >= (size_t)NROW * D_DIM * 4) ? (float*)d_ws : nullptr;
    (void)in_sizes; (void)n_in; (void)out_size;

    vq_prep<<<dim3(64), dim3(256), 0, stream>>>(e, eh, eeg, cntp, keys, out);
    vq_prep_z<<<dim3(NPART), dim3(256), 0, stream>>>(z, zh, zt32, zpart);
    vq_main_mfma<<<dim3(NROW / 128), dim3(256), 0, stream>>>(zh, eh, eeg, out, cntp, list1, list2, candp);
    vq_loss<<<dim3(1), dim3(256), 0, stream>>>(zpart, out);
    vq_fixup_lite<<<dim3(512), dim3(256), 0, stream>>>(z, zt32, e, eeg, out, list1, cntp, candp);
    vq_fixup_full<<<dim3(512), dim3(256), 0, stream>>>(z, zt32, e, eeg, list2, cntp, keys);
    vq_conv<<<dim3(1), dim3(256), 0, stream>>>(out, list2, cntp, keys);
    vq_out<<<dim3(512), dim3(256), 0, stream>>>(e, out);
}

// Round 15
// 509.090 us; speedup vs baseline: 1.1669x; 1.1669x over previous
//
#include <hip/hip_runtime.h>

typedef unsigned short u16;
typedef unsigned int   u32;
typedef unsigned long long u64;

#define B_DIM 16
#define D_DIM 768
#define T_DIM 4096
#define K_DIM 1024
#define NROW  (B_DIM * T_DIM)   // 65536 rows (b*T + t)
#define NPART (16 * 12 * 64)    // prep_z grid = 12288

// out layout (float32): out[0]=loss; out[1 + (b*D+d)*T + t]=z_q_st; out[IDX_OFF + b*T + t]=idx
#define IDX_OFF (1 + (size_t)B_DIM * D_DIM * T_DIM)

#define MARGIN_SI 185           // 7e-4 in 2^-18 units (2G numpy slack + ~16 sigma of eh-only score error)
#define SC_SCALE 3.814697265625e-06f   // 2^-18
#define INV_N 1.9868215e-8f            // 1/(16*768*4096)

#define LIST2_CAP 4096
#define ZPAD 772

// ---- scratch carved out of d_out's z_q region (overwritten by vq_out at the end) ----
#define ZH_OFF    ((size_t)64)                                  // bf16 z, [row][768], pre-swizzled (96 MB)
#define EH_OFF    (ZH_OFF + (size_t)NROW * D_DIM * 2)           // bf16 e hi
#define EL_OFF    (EH_OFF + (size_t)K_DIM * D_DIM * 2)          // (unused; layout stability)
#define EE_OFF    (EL_OFF + (size_t)K_DIM * D_DIM * 2)          // fp32 ||e_k||^2
#define CNT_OFF   (EE_OFF + (size_t)K_DIM * 4)                  // int cnt[0]=list1, cnt[1]=list2
#define LIST_OFF  (CNT_OFF + 64)                                // int list1 rows (<=65536)
#define LIST2_OFF (LIST_OFF + (size_t)NROW * 4)                 // int list2 rows (cap 4096)
#define CAND_OFF  (LIST2_OFF + (size_t)LIST2_CAP * 4)           // int2 (k2,k3) per row
#define ZPART_OFF (CAND_OFF + (size_t)NROW * 8)                 // float zpart[12288]
#define KEY_OFF   (ZPART_OFF + (size_t)NPART * 4)               // u64 keys (cap 4096)

static __device__ inline u16 f2bf(float x) {
    u32 u = __float_as_uint(x);
    u += 0x7fffu + ((u >> 16) & 1u);
    return (u16)(u >> 16);
}

typedef __attribute__((ext_vector_type(8))) short short8v;
typedef __attribute__((ext_vector_type(4))) float float4v;

static __device__ inline void gload16(const u16* g, u16* l) {
    __builtin_amdgcn_global_load_lds(
        (const __attribute__((address_space(1))) u32*)g,
        (__attribute__((address_space(3))) u32*)(uintptr_t)(void*)l,
        16, 0, 0);
}

#define LEXLT(av, ak, bv, bk) ((av) < (bv) || ((av) == (bv) && (ak) < (bk)))

// branchless sorted-insert of x into k1<=k2<=k3 (keep 3 smallest), 5 ops.
static __device__ inline void insk(int x, int& k1, int& k2, int& k3) {
    int t = max(k1, x);
    k1 = min(k1, x);
    int u = max(k2, t);
    k2 = min(k2, t);
    k3 = min(k3, u);
}

// ---------------- fused prep: ||e||^2 + e hi split (swizzled) + zero counters/loss + init keys ----------------
__global__ __launch_bounds__(256) void vq_prep(const float* __restrict__ e,
                                               u16* __restrict__ eh,
                                               float* __restrict__ ee, int* __restrict__ cnt,
                                               u64* __restrict__ keys,
                                               float* __restrict__ out)
{
    const int tid = threadIdx.x, bid = blockIdx.x;
    if (bid == 0 && tid == 0) { cnt[0] = 0; cnt[1] = 0; out[0] = 0.0f; }
    int lin = bid * 256 + tid;
    if (lin < LIST2_CAP) keys[lin] = ~0ull;
    if (bid < 4) {
        int k = bid * 256 + tid;
        const float* er = e + (size_t)k * D_DIM;
        double s = 0.0;
        for (int d = 0; d < D_DIM; ++d) { double ed = (double)er[d]; s = fma(ed, ed, s); }
        ee[k] = (float)s;
    }
    for (int t = lin; t < K_DIM * 96; t += 64 * 256) {
        int k = t / 96;
        int ch = t - k * 96;              // 8-elem chunk id
        const float* src = e + (size_t)k * D_DIM + ch * 8;
        u16 h[8];
        #pragma unroll
        for (int q = 0; q < 8; ++q) h[q] = f2bf(src[q]);
        int dst = (ch >> 3) * 64 + (((ch & 7) ^ (k & 7)) << 3);
        *(uint4*)(eh + (size_t)k * D_DIM + dst) = *(const uint4*)h;
    }
}

// ---------------- prep: z transpose -> bf16 zh (swizzled) + optional fp32 zt32 + z^2 partials ----------------
__global__ __launch_bounds__(256) void vq_prep_z(const float* __restrict__ z, u16* __restrict__ zh,
                                                 float* __restrict__ zt32, float* __restrict__ zpart)
{
    __shared__ u16 tmp[64][72];
    __shared__ float tmp32[64][66];
    __shared__ double lredd[4];
    int bi = blockIdx.x;
    int dg = bi % 12;
    int tg = (bi / 12) % 64;
    int b  = bi / (12 * 64);
    int tid = threadIdx.x;
    int tl4 = (tid & 15) * 4;
    int dl  = tid >> 4;
    double s = 0.0;
    #pragma unroll
    for (int p = 0; p < 4; ++p) {
        int d = dg * 64 + p * 16 + dl;
        const float* src = z + ((size_t)b * D_DIM + d) * T_DIM + tg * 64 + tl4;
        float4 v = *(const float4*)src;
        tmp[tl4 + 0][p * 16 + dl] = f2bf(v.x);
        tmp[tl4 + 1][p * 16 + dl] = f2bf(v.y);
        tmp[tl4 + 2][p * 16 + dl] = f2bf(v.z);
        tmp[tl4 + 3][p * 16 + dl] = f2bf(v.w);
        tmp32[tl4 + 0][p * 16 + dl] = v.x;
        tmp32[tl4 + 1][p * 16 + dl] = v.y;
        tmp32[tl4 + 2][p * 16 + dl] = v.z;
        tmp32[tl4 + 3][p * 16 + dl] = v.w;
        s = fma((double)v.x, (double)v.x, s);
        s = fma((double)v.y, (double)v.y, s);
        s = fma((double)v.z, (double)v.z, s);
        s = fma((double)v.w, (double)v.w, s);
    }
    #pragma unroll
    for (int m = 1; m < 64; m <<= 1) s += __shfl_xor(s, m);
    if ((tid & 63) == 0) lredd[tid >> 6] = s;
    __syncthreads();
    if (tid == 0) zpart[bi] = (float)(lredd[0] + lredd[1] + lredd[2] + lredd[3]);
    #pragma unroll
    for (int w = 0; w < 2; ++w) {
        int lin = tid * 2 + w;            // 0..511 = 64 rows x 8 chunks
        int tl  = lin >> 3;
        int c   = lin & 7;
        size_t row_g = (size_t)b * T_DIM + tg * 64 + tl;
        int cs = c ^ ((int)row_g & 7);
        uint4 val = *(const uint4*)&tmp[tl][c * 8];
        *(uint4*)(zh + row_g * D_DIM + dg * 64 + cs * 8) = val;
    }
    if (zt32) {
        #pragma unroll
        for (int w = 0; w < 4; ++w) {
            int lin = tid * 4 + w;        // 0..1023 = 64 rows x 16 float4
            int tl = lin >> 4;
            int cq = lin & 15;
            size_t row_g = (size_t)b * T_DIM + tg * 64 + tl;
            float4 v;
            v.x = tmp32[tl][cq * 4 + 0];
            v.y = tmp32[tl][cq * 4 + 1];
            v.z = tmp32[tl][cq * 4 + 2];
            v.w = tmp32[tl][cq * 4 + 3];
            *(float4*)(zt32 + row_g * D_DIM + dg * 64 + cq * 4) = v;
        }
    }
}

// ---------------- reduce z^2 partials into loss ----------------
__global__ __launch_bounds__(256) void vq_loss(const float* __restrict__ zpart, float* __restrict__ out)
{
    __shared__ double r[4];
    double s = 0.0;
    for (int i = threadIdx.x; i < NPART; i += 256) s += (double)zpart[i];
    #pragma unroll
    for (int m = 1; m < 64; m <<= 1) s += __shfl_xor(s, m);
    if ((threadIdx.x & 63) == 0) r[threadIdx.x >> 6] = s;
    __syncthreads();
    if (threadIdx.x == 0) atomicAdd(out, (float)((r[0] + r[1] + r[2] + r[3]) * (double)INV_N));
}

// ---------------- main: bf16 MFMA scores (eh only), packed-key top-3 + routing + sc-sum ----------------
// (256,2): natural footprint 84 VGPR + 64 acc = 148 unified; forcing 4 waves/EU spills (r14: +134 MB scratch).
__global__ __launch_bounds__(256, 2) void vq_main_mfma(const u16* __restrict__ zh,
                                                       const u16* __restrict__ eh,
                                                       const float* __restrict__ ee_g,
                                                       float* __restrict__ out,
                                                       int* __restrict__ cnt,
                                                       int* __restrict__ list1,
                                                       int* __restrict__ list2,
                                                       int2* __restrict__ cand)
{
    __shared__ u16 zt[128 * 64];
    __shared__ u16 eht[128 * 64];
    __shared__ float eeS[K_DIM];              // ||e||^2 * 2^18
    __shared__ int pk3[128][2][3];
    __shared__ float scred[2];

    const int tid  = threadIdx.x;
    const int wid  = tid >> 6;
    const int lane = tid & 63;
    const int wm = wid >> 1, wn = wid & 1;
    const int l15 = lane & 15, l4 = lane >> 4;
    const int row_block = blockIdx.x * 128;

    for (int i = tid; i < K_DIM; i += 256) eeS[i] = ee_g[i] * 262144.0f;

    int kq1[16], kq2[16], kq3[16];
    #pragma unroll
    for (int i = 0; i < 16; ++i) { kq1[i] = 0x7fffffff; kq2[i] = 0x7fffffff; kq3[i] = 0x7fffffff; }

    const int r8 = lane >> 3;
    const int ch = lane & 7;

    for (int n0 = 0; n0 < 8; ++n0) {
        float4v acc[4][4];
        #pragma unroll
        for (int mf = 0; mf < 4; ++mf)
            #pragma unroll
            for (int nf = 0; nf < 4; ++nf) acc[mf][nf] = (float4v)0.0f;

        for (int d0i = 0; d0i < 12; ++d0i) {
            const int d0 = d0i * 64;
            __syncthreads();
            #pragma unroll
            for (int q = 0; q < 4; ++q) {
                int lr = wid * 32 + q * 8;
                gload16(zh + (size_t)(row_block + lr + r8) * D_DIM + d0 + ch * 8, &zt[lr * 64]);
            }
            #pragma unroll
            for (int q = 0; q < 4; ++q) {
                int lr = wid * 32 + q * 8;
                gload16(eh + (size_t)(n0 * 128 + lr + r8) * D_DIM + d0 + ch * 8, &eht[lr * 64]);
            }
            __syncthreads();

            #pragma unroll
            for (int s = 0; s < 2; ++s) {
                short8v a[4], bh4[4];
                #pragma unroll
                for (int mf = 0; mf < 4; ++mf) {
                    int r = wm * 64 + mf * 16 + l15;
                    int cs = (s * 4 + l4) ^ (r & 7);
                    a[mf] = *(const short8v*)&zt[r * 64 + cs * 8];
                }
                #pragma unroll
                for (int nf = 0; nf < 4; ++nf) {
                    int r = wn * 64 + nf * 16 + l15;
                    int cs = (s * 4 + l4) ^ (r & 7);
                    bh4[nf] = *(const short8v*)&eht[r * 64 + cs * 8];
                }
                #pragma unroll
                for (int mf = 0; mf < 4; ++mf)
                    #pragma unroll
                    for (int nf = 0; nf < 4; ++nf)
                        acc[mf][nf] = __builtin_amdgcn_mfma_f32_16x16x32_bf16(a[mf], bh4[nf], acc[mf][nf], 0, 0, 0);
            }
        }

        // fold: key = ((int)((ee - 2*acc) * 2^18) << 10) + code ; keep 3 smallest per slot
        #pragma unroll
        for (int nf = 0; nf < 4; ++nf) {
            int kg = n0 * 128 + wn * 64 + nf * 16 + l15;
            float eev = eeS[kg];
            #pragma unroll
            for (int mf = 0; mf < 4; ++mf)
                #pragma unroll
                for (int rr = 0; rr < 4; ++rr) {
                    float sc2 = fmaf(acc[mf][nf][rr], -524288.0f, eev);   // sc * 2^18
                    int si = (int)sc2;
                    int key = (si << 10) + kg;
                    const int slot = mf * 4 + rr;
                    insk(key, kq1[slot], kq2[slot], kq3[slot]);
                }
        }
    }

    // merge across the 16 lanes sharing l4 (masks 1,2,4,8)
    #pragma unroll
    for (int m = 1; m < 16; m <<= 1) {
        #pragma unroll
        for (int i = 0; i < 16; ++i) {
            int o1 = __shfl_xor(kq1[i], m);
            int o2 = __shfl_xor(kq2[i], m);
            int o3 = __shfl_xor(kq3[i], m);
            insk(o1, kq1[i], kq2[i], kq3[i]);
            insk(o2, kq1[i], kq2[i], kq3[i]);
            insk(o3, kq1[i], kq2[i], kq3[i]);
        }
    }

    // publish per-half top-3, merge halves, route
    if (l15 == 0) {
        #pragma unroll
        for (int mf = 0; mf < 4; ++mf)
            #pragma unroll
            for (int rr = 0; rr < 4; ++rr) {
                int slot = mf * 4 + rr;
                int rl = wm * 64 + mf * 16 + l4 * 4 + rr;   // 0..127
                pk3[rl][wn][0] = kq1[slot];
                pk3[rl][wn][1] = kq2[slot];
                pk3[rl][wn][2] = kq3[slot];
            }
    }
    __syncthreads();
    float scf = 0.0f;
    if (tid < 128) {
        int a1 = pk3[tid][0][0], a2 = pk3[tid][0][1], a3 = pk3[tid][0][2];
        insk(pk3[tid][1][0], a1, a2, a3);
        insk(pk3[tid][1][1], a1, a2, a3);
        insk(pk3[tid][1][2], a1, a2, a3);
        int s1 = a1 >> 10, s2 = a2 >> 10, s3 = a3 >> 10;   // arithmetic shift -> si
        int row = row_block + tid;
        out[IDX_OFF + row] = (float)(a1 & 1023);
        scf = (float)s1 * SC_SCALE;
        if (s3 - s1 < MARGIN_SI) {
            int p = atomicAdd(&cnt[1], 1);
            if (p < LIST2_CAP) list2[p] = row;
        } else if (s2 - s1 < MARGIN_SI) {
            int p = atomicAdd(&cnt[0], 1);
            list1[p] = row;
            cand[row] = make_int2(a2 & 1023, a3 & 1023);
        }
    }
    // sc-sum for loss (waves 2,3 contribute 0)
    #pragma unroll
    for (int m = 1; m < 64; m <<= 1) scf += __shfl_xor(scf, m);
    if (lane == 0 && wid < 2) scred[wid] = scf;
    __syncthreads();
    if (tid == 0) atomicAdd(out, (scred[0] + scred[1]) * INV_N);
}

// ---------------- fixup-lite: exact numpy-fp32 rescore of {k1,k2,k3} per flagged row ----------------
__global__ __launch_bounds__(256) void vq_fixup_lite(const float* __restrict__ z,
                                                     const float* __restrict__ zt32,
                                                     const float* __restrict__ e,
                                                     const float* __restrict__ ee,
                                                     float* __restrict__ out,
                                                     const int* __restrict__ list1,
                                                     const int* __restrict__ cnt,
                                                     const int2* __restrict__ cand)
{
    __shared__ float zr[16][776];
    __shared__ double afl[16];
    __shared__ int rowsL[16];
    __shared__ int candL[16][3];
    __shared__ float dqL[16][3];

    const int tid = threadIdx.x;
    int total = cnt[0];
    if (total > NROW) total = NROW;
    int ngroups = (total + 15) >> 4;

    for (int g = blockIdx.x; g < ngroups; g += gridDim.x) {
        int nr = total - g * 16; if (nr > 16) nr = 16;
        __syncthreads();
        if (tid < 16) {
            int row = list1[g * 16 + ((tid < nr) ? tid : 0)];
            rowsL[tid] = row;
            candL[tid][0] = (int)out[IDX_OFF + row];
            int2 cc = cand[row];
            candL[tid][1] = cc.x;
            candL[tid][2] = cc.y;
        }
        __syncthreads();
        if (zt32) {
            #pragma unroll
            for (int j = 0; j < 12; ++j) {
                int lin = tid + 256 * j;          // 0..3071 = 16 rows x 192 float4
                int r = lin / 192;
                int dq = (lin - r * 192) * 4;
                *(float4*)&zr[r][dq] = *(const float4*)(zt32 + (size_t)rowsL[r] * D_DIM + dq);
            }
        } else {
            int r = tid >> 4, sub = tid & 15;
            int row = rowsL[r];
            int b = row >> 12, t = row & 4095;
            const float* zp = z + (size_t)b * D_DIM * T_DIM + t;
            #pragma unroll 4
            for (int j = 0; j < 48; ++j) {
                int d = sub + 16 * j;
                zr[r][d] = zp[(size_t)d * T_DIM];
            }
        }
        __syncthreads();
        {   // A = fl32(fp64 sum z^2) (any assoc: grid-shift invariance)
            int r = tid >> 4, sub = tid & 15;
            double s = 0.0;
            for (int d = sub; d < D_DIM; d += 16) { double zd = (double)zr[r][d]; s = fma(zd, zd, s); }
            #pragma unroll
            for (int m = 1; m < 16; m <<= 1) s += __shfl_xor(s, m);
            if (sub == 0) afl[r] = s;
        }
        __syncthreads();
        if (tid < 96) {
            int c = tid >> 5;             // candidate 0..2
            int p = (tid >> 4) & 1;       // panel 0/1
            int r = tid & 15;             // row slot
            int kk = candL[r][c];
            const float* ep = e + (size_t)kk * D_DIM + p * 384;
            const float* zp = &zr[r][p * 384];
            float a0 = 0.0f;
            #pragma unroll 8
            for (int j = 0; j < 96; ++j) {
                float4 ev = *(const float4*)(ep + j * 4);
                float4 zv = *(const float4*)(zp + j * 4);
                a0 = fmaf(zv.x, ev.x, a0);
                a0 = fmaf(zv.y, ev.y, a0);
                a0 = fmaf(zv.z, ev.z, a0);
                a0 = fmaf(zv.w, ev.w, a0);
            }
            float other = __shfl_xor(a0, 16);
            if (p == 0) {
                float M  = a0 + other;                 // fl(S1+S2), OpenBLAS 384-panel split
                float t1 = (float)afl[r] + ee[kk];     // fl(A+E)
                dqL[r][c] = t1 - 2.0f * M;             // fl(fl(A+E) - 2M)
            }
        }
        __syncthreads();
        if (tid < nr) {
            float dv = dqL[tid][0]; int dk = candL[tid][0];
            #pragma unroll
            for (int c = 1; c < 3; ++c) {
                float v = dqL[tid][c]; int k2 = candL[tid][c];
                if (LEXLT(v, k2, dv, dk)) { dv = v; dk = k2; }
            }
            out[IDX_OFF + rowsL[tid]] = (float)dk;
        }
    }
}

// ---------------- fixup-full: exact 1024-code scan, sliced 8-ways across blocks ----------------
// thread map: p = t&1 (panel), r = (t>>1)&7 (row), c = t>>4 (code lane 0..15)
// slice s covers codes [s*128, s*128+128) as 8 groups of 16; e read direct from global (L2, broadcast)
__global__ __launch_bounds__(256) void vq_fixup_full(const float* __restrict__ z,
                                                     const float* __restrict__ zt32,
                                                     const float* __restrict__ e,
                                                     const float* __restrict__ ee,
                                                     const int* __restrict__ list2,
                                                     const int* __restrict__ cnt,
                                                     u64* __restrict__ keys)
{
    __shared__ float zr[8][ZPAD];
    __shared__ double afl[8];
    __shared__ int rowsL[8];
    __shared__ float dvL[8][17];
    __shared__ int   dkL[8][17];

    const int tid = threadIdx.x;
    const int p = tid & 1;
    const int r = (tid >> 1) & 7;
    const int c = tid >> 4;
    int total = cnt[1];
    if (total > LIST2_CAP) total = LIST2_CAP;
    if (total == 0) return;
    int nchunk = (total + 7) >> 3;
    int ntasks = nchunk * 8;

    for (int task = blockIdx.x; task < ntasks; task += gridDim.x) {
        int cj = task >> 3;
        int slice = task & 7;
        int nr = total - cj * 8; if (nr > 8) nr = 8;
        __syncthreads();
        if (tid < 8) rowsL[tid] = list2[cj * 8 + ((tid < nr) ? tid : 0)];
        __syncthreads();
        if (zt32) {
            #pragma unroll
            for (int j = 0; j < 6; ++j) {
                int lin = tid + 256 * j;          // 0..1535 = 8 rows x 192 float4
                int r2 = lin / 192;
                int dq = (lin - r2 * 192) * 4;
                *(float4*)&zr[r2][dq] = *(const float4*)(zt32 + (size_t)rowsL[r2] * D_DIM + dq);
            }
        } else {
            int rs = tid >> 5, sub = tid & 31;
            int row = rowsL[rs];
            int b = row >> 12, t = row & 4095;
            const float* zp = z + (size_t)b * D_DIM * T_DIM + t;
            #pragma unroll 4
            for (int j = 0; j < 24; ++j) {
                int d = sub + 32 * j;
                zr[rs][d] = zp[(size_t)d * T_DIM];
            }
        }
        __syncthreads();
        {   // A = fl32(fp64 sum z^2)
            int rs = tid >> 5, sub = tid & 31;
            double s = 0.0;
            for (int d = sub; d < D_DIM; d += 32) { double zd = (double)zr[rs][d]; s = fma(zd, zd, s); }
            #pragma unroll
            for (int m = 1; m < 32; m <<= 1) s += __shfl_xor(s, m);
            if (sub == 0) afl[rs] = s;
        }
        __syncthreads();
        const float Af = (float)afl[r];
        const float* zp = &zr[r][p * 384];

        float bd = 3.4e38f;
        int   bkk = 0x7fffffff;

        #pragma unroll 2
        for (int g2 = 0; g2 < 8; ++g2) {
            int code = slice * 128 + g2 * 16 + c;
            const float* ep = e + (size_t)code * D_DIM + p * 384;
            float a0 = 0.0f;
            #pragma unroll 8
            for (int j = 0; j < 96; ++j) {
                float4 zv = *(const float4*)(zp + j * 4);
                float4 ev = *(const float4*)(ep + j * 4);
                a0 = fmaf(zv.x, ev.x, a0);
                a0 = fmaf(zv.y, ev.y, a0);
                a0 = fmaf(zv.z, ev.z, a0);
                a0 = fmaf(zv.w, ev.w, a0);
            }
            float other = __shfl_xor(a0, 1);
            if (p == 0) {
                float M  = a0 + other;            // fl(S1+S2), OpenBLAS 384-panel split
                float t1 = Af + ee[code];         // fl(A+E)
                float dq = t1 - 2.0f * M;         // fl(fl(A+E) - 2M)
                if (LEXLT(dq, code, bd, bkk)) { bd = dq; bkk = code; }
            }
        }

        if (p == 0) { dvL[r][c] = bd; dkL[r][c] = bkk; }
        __syncthreads();
        if (tid < 8 && tid < nr) {
            float v = dvL[tid][0]; int kk = dkL[tid][0];
            #pragma unroll
            for (int i = 1; i < 16; ++i) {
                float v2 = dvL[tid][i]; int k2 = dkL[tid][i];
                if (LEXLT(v2, k2, v, kk)) { v = v2; kk = k2; }
            }
            u64 key = ((u64)__float_as_uint(v) << 32) | (u64)(u32)kk;
            atomicMin(&keys[cj * 8 + tid], key);
        }
        __syncthreads();
    }
}

// ---------------- convert full-scan keys -> idx ----------------
__global__ __launch_bounds__(256) void vq_conv(float* __restrict__ out,
                                               const int* __restrict__ list2,
                                               const int* __restrict__ cnt,
                                               const u64* __restrict__ keys)
{
    int total = cnt[1];
    if (total > LIST2_CAP) total = LIST2_CAP;
    for (int i = threadIdx.x; i < total; i += 256) {
        out[IDX_OFF + list2[i]] = (float)(u32)(keys[i] & 0xffffffffu);
    }
}

// ---------------- gather z_q -> transposed write (loss already accumulated) ----------------
__global__ __launch_bounds__(256) void vq_out(const float* __restrict__ e,
                                              float* __restrict__ out)
{
    const int tid  = threadIdx.x;
    const int mIdx = blockIdx.x;
    const int b    = mIdx >> 5;
    const int t0   = (mIdx & 31) * 128;

    const int t  = tid & 127;
    const int ds = tid >> 7;
    const int gt = t0 + t;
    const int k  = (int)out[IDX_OFF + (size_t)b * T_DIM + gt];
    const float* er = e + (size_t)k * D_DIM;
    for (int d0 = ds * 4; d0 < D_DIM; d0 += 8) {
        float4 v = *(const float4*)(er + d0);
        float vv[4];
        *(float4*)vv = v;
        #pragma unroll
        for (int j = 0; j < 4; ++j) {
            size_t o = (size_t)(b * D_DIM + d0 + j) * T_DIM + gt;
            out[1 + o] = vv[j];
        }
    }
}

extern "C" void kernel_launch(void* const* d_in, const int* in_sizes, int n_in,
                              void* d_out, int out_size, void* d_ws, size_t ws_size,
                              hipStream_t stream) {
    const float* z = (const float*)d_in[0];
    const float* e = (const float*)d_in[1];
    float* out = (float*)d_out;
    char* ob = (char*)d_out;
    u16*   zh    = (u16*)(ob + ZH_OFF);
    u16*   eh    = (u16*)(ob + EH_OFF);
    float* eeg   = (float*)(ob + EE_OFF);
    int*   cntp  = (int*)(ob + CNT_OFF);
    int*   list1 = (int*)(ob + LIST_OFF);
    int*   list2 = (int*)(ob + LIST2_OFF);
    int2*  candp = (int2*)(ob + CAND_OFF);
    float* zpart = (float*)(ob + ZPART_OFF);
    u64*   keys  = (u64*)(ob + KEY_OFF);
    // fp32 transposed z lives in d_ws when it fits; else fall back to strided gathers
    float* zt32 = (ws_size >= (size_t)NROW * D_DIM * 4) ? (float*)d_ws : nullptr;
    (void)in_sizes; (void)n_in; (void)out_size;

    vq_prep<<<dim3(64), dim3(256), 0, stream>>>(e, eh, eeg, cntp, keys, out);
    vq_prep_z<<<dim3(NPART), dim3(256), 0, stream>>>(z, zh, zt32, zpart);
    vq_main_mfma<<<dim3(NROW / 128), dim3(256), 0, stream>>>(zh, eh, eeg, out, cntp, list1, list2, candp);
    vq_loss<<<dim3(1), dim3(256), 0, stream>>>(zpart, out);
    vq_fixup_lite<<<dim3(512), dim3(256), 0, stream>>>(z, zt32, e, eeg, out, list1, cntp, candp);
    vq_fixup_full<<<dim3(512), dim3(256), 0, stream>>>(z, zt32, e, eeg, list2, cntp, keys);
    vq_conv<<<dim3(1), dim3(256), 0, stream>>>(out, list2, cntp, keys);
    vq_out<<<dim3(512), dim3(256), 0, stream>>>(e, out);
}

// Round 16
// 474.769 us; speedup vs baseline: 1.2512x; 1.0723x over previous
//
#include <hip/hip_runtime.h>

typedef unsigned short u16;
typedef unsigned int   u32;
typedef unsigned long long u64;

#define B_DIM 16
#define D_DIM 768
#define T_DIM 4096
#define K_DIM 1024
#define NROW  (B_DIM * T_DIM)   // 65536 rows (b*T + t)
#define NPART (16 * 12 * 64)    // prep_z grid = 12288

// out layout (float32): out[0]=loss; out[1 + (b*D+d)*T + t]=z_q_st; out[IDX_OFF + b*T + t]=idx
#define IDX_OFF (1 + (size_t)B_DIM * D_DIM * T_DIM)

#define MARGIN_SI 185           // 7e-4 in 2^-18 units (2G numpy slack + ~16 sigma of eh-only score error)
#define SC_SCALE 3.814697265625e-06f   // 2^-18
#define INV_N 1.9868215e-8f            // 1/(16*768*4096)

#define LIST2_CAP 4096
#define ZPAD 772

// ---- scratch carved out of d_out's z_q region (overwritten by vq_out at the end) ----
#define ZH_OFF    ((size_t)64)                                  // bf16 z, [row][768], pre-swizzled (96 MB)
#define EH_OFF    (ZH_OFF + (size_t)NROW * D_DIM * 2)           // bf16 e hi
#define EL_OFF    (EH_OFF + (size_t)K_DIM * D_DIM * 2)          // (unused; layout stability)
#define EE_OFF    (EL_OFF + (size_t)K_DIM * D_DIM * 2)          // fp32 ||e_k||^2
#define CNT_OFF   (EE_OFF + (size_t)K_DIM * 4)                  // int cnt[0]=list1, cnt[1]=list2
#define LIST_OFF  (CNT_OFF + 64)                                // int list1 rows (<=65536)
#define LIST2_OFF (LIST_OFF + (size_t)NROW * 4)                 // int list2 rows (cap 4096)
#define CAND_OFF  (LIST2_OFF + (size_t)LIST2_CAP * 4)           // int2 (k2,k3) per row
#define ZPART_OFF (CAND_OFF + (size_t)NROW * 8)                 // float zpart[12288]
#define KEY_OFF   (ZPART_OFF + (size_t)NPART * 4)               // u64 keys (cap 4096)

static __device__ inline u16 f2bf(float x) {
    u32 u = __float_as_uint(x);
    u += 0x7fffu + ((u >> 16) & 1u);
    return (u16)(u >> 16);
}

typedef __attribute__((ext_vector_type(8))) short short8v;
typedef __attribute__((ext_vector_type(4))) float float4v;

static __device__ inline void gload16(const u16* g, u16* l) {
    __builtin_amdgcn_global_load_lds(
        (const __attribute__((address_space(1))) u32*)g,
        (__attribute__((address_space(3))) u32*)(uintptr_t)(void*)l,
        16, 0, 0);
}

#define LEXLT(av, ak, bv, bk) ((av) < (bv) || ((av) == (bv) && (ak) < (bk)))

// branchless sorted-insert of x into k1<=k2<=k3 (keep 3 smallest), 5 ops.
static __device__ inline void insk(int x, int& k1, int& k2, int& k3) {
    int t = max(k1, x);
    k1 = min(k1, x);
    int u = max(k2, t);
    k2 = min(k2, t);
    k3 = min(k3, u);
}

// ---------------- fused prep: ||e||^2 + e hi split (swizzled) + zero counters/loss + init keys ----------------
__global__ __launch_bounds__(256) void vq_prep(const float* __restrict__ e,
                                               u16* __restrict__ eh,
                                               float* __restrict__ ee, int* __restrict__ cnt,
                                               u64* __restrict__ keys,
                                               float* __restrict__ out)
{
    const int tid = threadIdx.x, bid = blockIdx.x;
    if (bid == 0 && tid == 0) { cnt[0] = 0; cnt[1] = 0; out[0] = 0.0f; }
    int lin = bid * 256 + tid;
    if (lin < LIST2_CAP) keys[lin] = ~0ull;
    if (bid < 4) {
        int k = bid * 256 + tid;
        const float* er = e + (size_t)k * D_DIM;
        double s = 0.0;
        for (int d = 0; d < D_DIM; ++d) { double ed = (double)er[d]; s = fma(ed, ed, s); }
        ee[k] = (float)s;
    }
    for (int t = lin; t < K_DIM * 96; t += 64 * 256) {
        int k = t / 96;
        int ch = t - k * 96;              // 8-elem chunk id
        const float* src = e + (size_t)k * D_DIM + ch * 8;
        u16 h[8];
        #pragma unroll
        for (int q = 0; q < 8; ++q) h[q] = f2bf(src[q]);
        int dst = (ch >> 3) * 64 + (((ch & 7) ^ (k & 7)) << 3);
        *(uint4*)(eh + (size_t)k * D_DIM + dst) = *(const uint4*)h;
    }
}

// ---------------- prep: z transpose -> bf16 zh (swizzled) + optional fp32 zt32 + z^2 partials ----------------
__global__ __launch_bounds__(256) void vq_prep_z(const float* __restrict__ z, u16* __restrict__ zh,
                                                 float* __restrict__ zt32, float* __restrict__ zpart)
{
    __shared__ u16 tmp[64][72];
    __shared__ float tmp32[64][66];
    __shared__ double lredd[4];
    int bi = blockIdx.x;
    int dg = bi % 12;
    int tg = (bi / 12) % 64;
    int b  = bi / (12 * 64);
    int tid = threadIdx.x;
    int tl4 = (tid & 15) * 4;
    int dl  = tid >> 4;
    double s = 0.0;
    #pragma unroll
    for (int p = 0; p < 4; ++p) {
        int d = dg * 64 + p * 16 + dl;
        const float* src = z + ((size_t)b * D_DIM + d) * T_DIM + tg * 64 + tl4;
        float4 v = *(const float4*)src;
        tmp[tl4 + 0][p * 16 + dl] = f2bf(v.x);
        tmp[tl4 + 1][p * 16 + dl] = f2bf(v.y);
        tmp[tl4 + 2][p * 16 + dl] = f2bf(v.z);
        tmp[tl4 + 3][p * 16 + dl] = f2bf(v.w);
        tmp32[tl4 + 0][p * 16 + dl] = v.x;
        tmp32[tl4 + 1][p * 16 + dl] = v.y;
        tmp32[tl4 + 2][p * 16 + dl] = v.z;
        tmp32[tl4 + 3][p * 16 + dl] = v.w;
        s = fma((double)v.x, (double)v.x, s);
        s = fma((double)v.y, (double)v.y, s);
        s = fma((double)v.z, (double)v.z, s);
        s = fma((double)v.w, (double)v.w, s);
    }
    #pragma unroll
    for (int m = 1; m < 64; m <<= 1) s += __shfl_xor(s, m);
    if ((tid & 63) == 0) lredd[tid >> 6] = s;
    __syncthreads();
    if (tid == 0) zpart[bi] = (float)(lredd[0] + lredd[1] + lredd[2] + lredd[3]);
    #pragma unroll
    for (int w = 0; w < 2; ++w) {
        int lin = tid * 2 + w;            // 0..511 = 64 rows x 8 chunks
        int tl  = lin >> 3;
        int c   = lin & 7;
        size_t row_g = (size_t)b * T_DIM + tg * 64 + tl;
        int cs = c ^ ((int)row_g & 7);
        uint4 val = *(const uint4*)&tmp[tl][c * 8];
        *(uint4*)(zh + row_g * D_DIM + dg * 64 + cs * 8) = val;
    }
    if (zt32) {
        #pragma unroll
        for (int w = 0; w < 4; ++w) {
            int lin = tid * 4 + w;        // 0..1023 = 64 rows x 16 float4
            int tl = lin >> 4;
            int cq = lin & 15;
            size_t row_g = (size_t)b * T_DIM + tg * 64 + tl;
            float4 v;
            v.x = tmp32[tl][cq * 4 + 0];
            v.y = tmp32[tl][cq * 4 + 1];
            v.z = tmp32[tl][cq * 4 + 2];
            v.w = tmp32[tl][cq * 4 + 3];
            *(float4*)(zt32 + row_g * D_DIM + dg * 64 + cq * 4) = v;
        }
    }
}

// ---------------- reduce z^2 partials into loss ----------------
__global__ __launch_bounds__(256) void vq_loss(const float* __restrict__ zpart, float* __restrict__ out)
{
    __shared__ double r[4];
    double s = 0.0;
    for (int i = threadIdx.x; i < NPART; i += 256) s += (double)zpart[i];
    #pragma unroll
    for (int m = 1; m < 64; m <<= 1) s += __shfl_xor(s, m);
    if ((threadIdx.x & 63) == 0) r[threadIdx.x >> 6] = s;
    __syncthreads();
    if (threadIdx.x == 0) atomicAdd(out, (float)((r[0] + r[1] + r[2] + r[3]) * (double)INV_N));
}

// ---------------- main: bf16 MFMA scores (eh only), n0-PAIRED tiles, packed-key top-3 + routing + sc-sum ----------------
// Pairing amortizes the z-tile staging + barrier drain over 2 codebook tiles:
// barriers 192->96 per block, zt global re-reads 8x->4x. acc doubles (128 f32) ->
// unified regs ~220 <= 256 cap at 2 waves/EU (no spill; r14 showed spill signature is WRITE_SIZE blowup).
__global__ __launch_bounds__(256, 2) void vq_main_mfma(const u16* __restrict__ zh,
                                                       const u16* __restrict__ eh,
                                                       const float* __restrict__ ee_g,
                                                       float* __restrict__ out,
                                                       int* __restrict__ cnt,
                                                       int* __restrict__ list1,
                                                       int* __restrict__ list2,
                                                       int2* __restrict__ cand)
{
    __shared__ u16 zt[128 * 64];
    __shared__ u16 eht[2][128 * 64];
    __shared__ float eeS[K_DIM];              // ||e||^2 * 2^18
    __shared__ int pk3[128][2][3];
    __shared__ float scred[2];

    const int tid  = threadIdx.x;
    const int wid  = tid >> 6;
    const int lane = tid & 63;
    const int wm = wid >> 1, wn = wid & 1;
    const int l15 = lane & 15, l4 = lane >> 4;
    const int row_block = blockIdx.x * 128;

    for (int i = tid; i < K_DIM; i += 256) eeS[i] = ee_g[i] * 262144.0f;

    int kq1[16], kq2[16], kq3[16];
    #pragma unroll
    for (int i = 0; i < 16; ++i) { kq1[i] = 0x7fffffff; kq2[i] = 0x7fffffff; kq3[i] = 0x7fffffff; }

    const int r8 = lane >> 3;
    const int ch = lane & 7;

    for (int np = 0; np < 4; ++np) {
        float4v acc[2][4][4];
        #pragma unroll
        for (int u = 0; u < 2; ++u)
            #pragma unroll
            for (int mf = 0; mf < 4; ++mf)
                #pragma unroll
                for (int nf = 0; nf < 4; ++nf) acc[u][mf][nf] = (float4v)0.0f;

        for (int d0i = 0; d0i < 12; ++d0i) {
            const int d0 = d0i * 64;
            __syncthreads();
            #pragma unroll
            for (int q = 0; q < 4; ++q) {
                int lr = wid * 32 + q * 8;
                gload16(zh + (size_t)(row_block + lr + r8) * D_DIM + d0 + ch * 8, &zt[lr * 64]);
            }
            #pragma unroll
            for (int u = 0; u < 2; ++u)
                #pragma unroll
                for (int q = 0; q < 4; ++q) {
                    int lr = wid * 32 + q * 8;
                    gload16(eh + (size_t)(np * 256 + u * 128 + lr + r8) * D_DIM + d0 + ch * 8,
                            &eht[u][lr * 64]);
                }
            __syncthreads();

            #pragma unroll
            for (int s = 0; s < 2; ++s) {
                short8v a[4], bh4[2][4];
                #pragma unroll
                for (int mf = 0; mf < 4; ++mf) {
                    int r = wm * 64 + mf * 16 + l15;
                    int cs = (s * 4 + l4) ^ (r & 7);
                    a[mf] = *(const short8v*)&zt[r * 64 + cs * 8];
                }
                #pragma unroll
                for (int u = 0; u < 2; ++u)
                    #pragma unroll
                    for (int nf = 0; nf < 4; ++nf) {
                        int r = wn * 64 + nf * 16 + l15;
                        int cs = (s * 4 + l4) ^ (r & 7);
                        bh4[u][nf] = *(const short8v*)&eht[u][r * 64 + cs * 8];
                    }
                #pragma unroll
                for (int u = 0; u < 2; ++u)
                    #pragma unroll
                    for (int mf = 0; mf < 4; ++mf)
                        #pragma unroll
                        for (int nf = 0; nf < 4; ++nf)
                            acc[u][mf][nf] = __builtin_amdgcn_mfma_f32_16x16x32_bf16(a[mf], bh4[u][nf], acc[u][mf][nf], 0, 0, 0);
            }
        }

        // fold: key = ((int)((ee - 2*acc) * 2^18) << 10) + code ; keep 3 smallest per slot
        // (fold order u=0 then u=1 == ascending n0 -> identical keys to unpaired version)
        #pragma unroll
        for (int u = 0; u < 2; ++u)
            #pragma unroll
            for (int nf = 0; nf < 4; ++nf) {
                int kg = (np * 2 + u) * 128 + wn * 64 + nf * 16 + l15;
                float eev = eeS[kg];
                #pragma unroll
                for (int mf = 0; mf < 4; ++mf)
                    #pragma unroll
                    for (int rr = 0; rr < 4; ++rr) {
                        float sc2 = fmaf(acc[u][mf][nf][rr], -524288.0f, eev);   // sc * 2^18
                        int si = (int)sc2;
                        int key = (si << 10) + kg;
                        const int slot = mf * 4 + rr;
                        insk(key, kq1[slot], kq2[slot], kq3[slot]);
                    }
            }
    }

    // merge across the 16 lanes sharing l4 (masks 1,2,4,8)
    #pragma unroll
    for (int m = 1; m < 16; m <<= 1) {
        #pragma unroll
        for (int i = 0; i < 16; ++i) {
            int o1 = __shfl_xor(kq1[i], m);
            int o2 = __shfl_xor(kq2[i], m);
            int o3 = __shfl_xor(kq3[i], m);
            insk(o1, kq1[i], kq2[i], kq3[i]);
            insk(o2, kq1[i], kq2[i], kq3[i]);
            insk(o3, kq1[i], kq2[i], kq3[i]);
        }
    }

    // publish per-half top-3, merge halves, route
    if (l15 == 0) {
        #pragma unroll
        for (int mf = 0; mf < 4; ++mf)
            #pragma unroll
            for (int rr = 0; rr < 4; ++rr) {
                int slot = mf * 4 + rr;
                int rl = wm * 64 + mf * 16 + l4 * 4 + rr;   // 0..127
                pk3[rl][wn][0] = kq1[slot];
                pk3[rl][wn][1] = kq2[slot];
                pk3[rl][wn][2] = kq3[slot];
            }
    }
    __syncthreads();
    float scf = 0.0f;
    if (tid < 128) {
        int a1 = pk3[tid][0][0], a2 = pk3[tid][0][1], a3 = pk3[tid][0][2];
        insk(pk3[tid][1][0], a1, a2, a3);
        insk(pk3[tid][1][1], a1, a2, a3);
        insk(pk3[tid][1][2], a1, a2, a3);
        int s1 = a1 >> 10, s2 = a2 >> 10, s3 = a3 >> 10;   // arithmetic shift -> si
        int row = row_block + tid;
        out[IDX_OFF + row] = (float)(a1 & 1023);
        scf = (float)s1 * SC_SCALE;
        if (s3 - s1 < MARGIN_SI) {
            int p = atomicAdd(&cnt[1], 1);
            if (p < LIST2_CAP) list2[p] = row;
        } else if (s2 - s1 < MARGIN_SI) {
            int p = atomicAdd(&cnt[0], 1);
            list1[p] = row;
            cand[row] = make_int2(a2 & 1023, a3 & 1023);
        }
    }
    // sc-sum for loss (waves 2,3 contribute 0)
    #pragma unroll
    for (int m = 1; m < 64; m <<= 1) scf += __shfl_xor(scf, m);
    if (lane == 0 && wid < 2) scred[wid] = scf;
    __syncthreads();
    if (tid == 0) atomicAdd(out, (scred[0] + scred[1]) * INV_N);
}

// ---------------- fixup-lite: exact numpy-fp32 rescore of {k1,k2,k3} per flagged row ----------------
__global__ __launch_bounds__(256) void vq_fixup_lite(const float* __restrict__ z,
                                                     const float* __restrict__ zt32,
                                                     const float* __restrict__ e,
                                                     const float* __restrict__ ee,
                                                     float* __restrict__ out,
                                                     const int* __restrict__ list1,
                                                     const int* __restrict__ cnt,
                                                     const int2* __restrict__ cand)
{
    __shared__ float zr[16][776];
    __shared__ double afl[16];
    __shared__ int rowsL[16];
    __shared__ int candL[16][3];
    __shared__ float dqL[16][3];

    const int tid = threadIdx.x;
    int total = cnt[0];
    if (total > NROW) total = NROW;
    int ngroups = (total + 15) >> 4;

    for (int g = blockIdx.x; g < ngroups; g += gridDim.x) {
        int nr = total - g * 16; if (nr > 16) nr = 16;
        __syncthreads();
        if (tid < 16) {
            int row = list1[g * 16 + ((tid < nr) ? tid : 0)];
            rowsL[tid] = row;
            candL[tid][0] = (int)out[IDX_OFF + row];
            int2 cc = cand[row];
            candL[tid][1] = cc.x;
            candL[tid][2] = cc.y;
        }
        __syncthreads();
        if (zt32) {
            #pragma unroll
            for (int j = 0; j < 12; ++j) {
                int lin = tid + 256 * j;          // 0..3071 = 16 rows x 192 float4
                int r = lin / 192;
                int dq = (lin - r * 192) * 4;
                *(float4*)&zr[r][dq] = *(const float4*)(zt32 + (size_t)rowsL[r] * D_DIM + dq);
            }
        } else {
            int r = tid >> 4, sub = tid & 15;
            int row = rowsL[r];
            int b = row >> 12, t = row & 4095;
            const float* zp = z + (size_t)b * D_DIM * T_DIM + t;
            #pragma unroll 4
            for (int j = 0; j < 48; ++j) {
                int d = sub + 16 * j;
                zr[r][d] = zp[(size_t)d * T_DIM];
            }
        }
        __syncthreads();
        {   // A = fl32(fp64 sum z^2) (any assoc: grid-shift invariance)
            int r = tid >> 4, sub = tid & 15;
            double s = 0.0;
            for (int d = sub; d < D_DIM; d += 16) { double zd = (double)zr[r][d]; s = fma(zd, zd, s); }
            #pragma unroll
            for (int m = 1; m < 16; m <<= 1) s += __shfl_xor(s, m);
            if (sub == 0) afl[r] = s;
        }
        __syncthreads();
        if (tid < 96) {
            int c = tid >> 5;             // candidate 0..2
            int p = (tid >> 4) & 1;       // panel 0/1
            int r = tid & 15;             // row slot
            int kk = candL[r][c];
            const float* ep = e + (size_t)kk * D_DIM + p * 384;
            const float* zp = &zr[r][p * 384];
            float a0 = 0.0f;
            #pragma unroll 8
            for (int j = 0; j < 96; ++j) {
                float4 ev = *(const float4*)(ep + j * 4);
                float4 zv = *(const float4*)(zp + j * 4);
                a0 = fmaf(zv.x, ev.x, a0);
                a0 = fmaf(zv.y, ev.y, a0);
                a0 = fmaf(zv.z, ev.z, a0);
                a0 = fmaf(zv.w, ev.w, a0);
            }
            float other = __shfl_xor(a0, 16);
            if (p == 0) {
                float M  = a0 + other;                 // fl(S1+S2), OpenBLAS 384-panel split
                float t1 = (float)afl[r] + ee[kk];     // fl(A+E)
                dqL[r][c] = t1 - 2.0f * M;             // fl(fl(A+E) - 2M)
            }
        }
        __syncthreads();
        if (tid < nr) {
            float dv = dqL[tid][0]; int dk = candL[tid][0];
            #pragma unroll
            for (int c = 1; c < 3; ++c) {
                float v = dqL[tid][c]; int k2 = candL[tid][c];
                if (LEXLT(v, k2, dv, dk)) { dv = v; dk = k2; }
            }
            out[IDX_OFF + rowsL[tid]] = (float)dk;
        }
    }
}

// ---------------- fixup-full: exact 1024-code scan, sliced 8-ways across blocks ----------------
__global__ __launch_bounds__(256) void vq_fixup_full(const float* __restrict__ z,
                                                     const float* __restrict__ zt32,
                                                     const float* __restrict__ e,
                                                     const float* __restrict__ ee,
                                                     const int* __restrict__ list2,
                                                     const int* __restrict__ cnt,
                                                     u64* __restrict__ keys)
{
    __shared__ float zr[8][ZPAD];
    __shared__ double afl[8];
    __shared__ int rowsL[8];
    __shared__ float dvL[8][17];
    __shared__ int   dkL[8][17];

    const int tid = threadIdx.x;
    const int p = tid & 1;
    const int r = (tid >> 1) & 7;
    const int c = tid >> 4;
    int total = cnt[1];
    if (total > LIST2_CAP) total = LIST2_CAP;
    if (total == 0) return;
    int nchunk = (total + 7) >> 3;
    int ntasks = nchunk * 8;

    for (int task = blockIdx.x; task < ntasks; task += gridDim.x) {
        int cj = task >> 3;
        int slice = task & 7;
        int nr = total - cj * 8; if (nr > 8) nr = 8;
        __syncthreads();
        if (tid < 8) rowsL[tid] = list2[cj * 8 + ((tid < nr) ? tid : 0)];
        __syncthreads();
        if (zt32) {
            #pragma unroll
            for (int j = 0; j < 6; ++j) {
                int lin = tid + 256 * j;          // 0..1535 = 8 rows x 192 float4
                int r2 = lin / 192;
                int dq = (lin - r2 * 192) * 4;
                *(float4*)&zr[r2][dq] = *(const float4*)(zt32 + (size_t)rowsL[r2] * D_DIM + dq);
            }
        } else {
            int rs = tid >> 5, sub = tid & 31;
            int row = rowsL[rs];
            int b = row >> 12, t = row & 4095;
            const float* zp = z + (size_t)b * D_DIM * T_DIM + t;
            #pragma unroll 4
            for (int j = 0; j < 24; ++j) {
                int d = sub + 32 * j;
                zr[rs][d] = zp[(size_t)d * T_DIM];
            }
        }
        __syncthreads();
        {   // A = fl32(fp64 sum z^2)
            int rs = tid >> 5, sub = tid & 31;
            double s = 0.0;
            for (int d = sub; d < D_DIM; d += 32) { double zd = (double)zr[rs][d]; s = fma(zd, zd, s); }
            #pragma unroll
            for (int m = 1; m < 32; m <<= 1) s += __shfl_xor(s, m);
            if (sub == 0) afl[rs] = s;
        }
        __syncthreads();
        const float Af = (float)afl[r];
        const float* zp = &zr[r][p * 384];

        float bd = 3.4e38f;
        int   bkk = 0x7fffffff;

        #pragma unroll 2
        for (int g2 = 0; g2 < 8; ++g2) {
            int code = slice * 128 + g2 * 16 + c;
            const float* ep = e + (size_t)code * D_DIM + p * 384;
            float a0 = 0.0f;
            #pragma unroll 8
            for (int j = 0; j < 96; ++j) {
                float4 zv = *(const float4*)(zp + j * 4);
                float4 ev = *(const float4*)(ep + j * 4);
                a0 = fmaf(zv.x, ev.x, a0);
                a0 = fmaf(zv.y, ev.y, a0);
                a0 = fmaf(zv.z, ev.z, a0);
                a0 = fmaf(zv.w, ev.w, a0);
            }
            float other = __shfl_xor(a0, 1);
            if (p == 0) {
                float M  = a0 + other;            // fl(S1+S2), OpenBLAS 384-panel split
                float t1 = Af + ee[code];         // fl(A+E)
                float dq = t1 - 2.0f * M;         // fl(fl(A+E) - 2M)
                if (LEXLT(dq, code, bd, bkk)) { bd = dq; bkk = code; }
            }
        }

        if (p == 0) { dvL[r][c] = bd; dkL[r][c] = bkk; }
        __syncthreads();
        if (tid < 8 && tid < nr) {
            float v = dvL[tid][0]; int kk = dkL[tid][0];
            #pragma unroll
            for (int i = 1; i < 16; ++i) {
                float v2 = dvL[tid][i]; int k2 = dkL[tid][i];
                if (LEXLT(v2, k2, v, kk)) { v = v2; kk = k2; }
            }
            u64 key = ((u64)__float_as_uint(v) << 32) | (u64)(u32)kk;
            atomicMin(&keys[cj * 8 + tid], key);
        }
        __syncthreads();
    }
}

// ---------------- convert full-scan keys -> idx ----------------
__global__ __launch_bounds__(256) void vq_conv(float* __restrict__ out,
                                               const int* __restrict__ list2,
                                               const int* __restrict__ cnt,
                                               const u64* __restrict__ keys)
{
    int total = cnt[1];
    if (total > LIST2_CAP) total = LIST2_CAP;
    for (int i = threadIdx.x; i < total; i += 256) {
        out[IDX_OFF + list2[i]] = (float)(u32)(keys[i] & 0xffffffffu);
    }
}

// ---------------- gather z_q -> transposed write (loss already accumulated) ----------------
__global__ __launch_bounds__(256) void vq_out(const float* __restrict__ e,
                                              float* __restrict__ out)
{
    const int tid  = threadIdx.x;
    const int mIdx = blockIdx.x;
    const int b    = mIdx >> 5;
    const int t0   = (mIdx & 31) * 128;

    const int t  = tid & 127;
    const int ds = tid >> 7;
    const int gt = t0 + t;
    const int k  = (int)out[IDX_OFF + (size_t)b * T_DIM + gt];
    const float* er = e + (size_t)k * D_DIM;
    for (int d0 = ds * 4; d0 < D_DIM; d0 += 8) {
        float4 v = *(const float4*)(er + d0);
        float vv[4];
        *(float4*)vv = v;
        #pragma unroll
        for (int j = 0; j < 4; ++j) {
            size_t o = (size_t)(b * D_DIM + d0 + j) * T_DIM + gt;
            out[1 + o] = vv[j];
        }
    }
}

extern "C" void kernel_launch(void* const* d_in, const int* in_sizes, int n_in,
                              void* d_out, int out_size, void* d_ws, size_t ws_size,
                              hipStream_t stream) {
    const float* z = (const float*)d_in[0];
    const float* e = (const float*)d_in[1];
    float* out = (float*)d_out;
    char* ob = (char*)d_out;
    u16*   zh    = (u16*)(ob + ZH_OFF);
    u16*   eh    = (u16*)(ob + EH_OFF);
    float* eeg   = (float*)(ob + EE_OFF);
    int*   cntp  = (int*)(ob + CNT_OFF);
    int*   list1 = (int*)(ob + LIST_OFF);
    int*   list2 = (int*)(ob + LIST2_OFF);
    int2*  candp = (int2*)(ob + CAND_OFF);
    float* zpart = (float*)(ob + ZPART_OFF);
    u64*   keys  = (u64*)(ob + KEY_OFF);
    // fp32 transposed z lives in d_ws when it fits; else fall back to strided gathers
    float* zt32 = (ws_size >= (size_t)NROW * D_DIM * 4) ? (float*)d_ws : nullptr;
    (void)in_sizes; (void)n_in; (void)out_size;

    vq_prep<<<dim3(64), dim3(256), 0, stream>>>(e, eh, eeg, cntp, keys, out);
    vq_prep_z<<<dim3(NPART), dim3(256), 0, stream>>>(z, zh, zt32, zpart);
    vq_main_mfma<<<dim3(NROW / 128), dim3(256), 0, stream>>>(zh, eh, eeg, out, cntp, list1, list2, candp);
    vq_loss<<<dim3(1), dim3(256), 0, stream>>>(zpart, out);
    vq_fixup_lite<<<dim3(512), dim3(256), 0, stream>>>(z, zt32, e, eeg, out, list1, cntp, candp);
    vq_fixup_full<<<dim3(512), dim3(256), 0, stream>>>(z, zt32, e, eeg, list2, cntp, keys);
    vq_conv<<<dim3(1), dim3(256), 0, stream>>>(out, list2, cntp, keys);
    vq_out<<<dim3(512), dim3(256), 0, stream>>>(e, out);
}

// Round 17
// 444.154 us; speedup vs baseline: 1.3375x; 1.0689x over previous
//
#include <hip/hip_runtime.h>

typedef unsigned short u16;
typedef unsigned int   u32;
typedef unsigned long long u64;

#define B_DIM 16
#define D_DIM 768
#define T_DIM 4096
#define K_DIM 1024
#define NROW  (B_DIM * T_DIM)   // 65536 rows (b*T + t)
#define NPART (16 * 12 * 64)    // prep_z grid = 12288

// out layout (float32): out[0]=loss; out[1 + (b*D+d)*T + t]=z_q_st; out[IDX_OFF + b*T + t]=idx
#define IDX_OFF (1 + (size_t)B_DIM * D_DIM * T_DIM)

#define MARGIN_SI 150           // 2G numpy slack (32 si) + ~12.8 sigma of eh-only score noise
#define SC_SCALE 3.814697265625e-06f   // 2^-18
#define INV_N 1.9868215e-8f            // 1/(16*768*4096)

#define LIST2_CAP 4096
#define ZPAD 772

// ---- scratch carved out of d_out's z_q region (overwritten by vq_out at the end) ----
#define ZH_OFF    ((size_t)64)                                  // bf16 z, [row][768], pre-swizzled (96 MB)
#define EH_OFF    (ZH_OFF + (size_t)NROW * D_DIM * 2)           // bf16 e hi
#define EL_OFF    (EH_OFF + (size_t)K_DIM * D_DIM * 2)          // (unused; layout stability)
#define EE_OFF    (EL_OFF + (size_t)K_DIM * D_DIM * 2)          // fp32 ||e_k||^2
#define CNT_OFF   (EE_OFF + (size_t)K_DIM * 4)                  // int cnt[0]=list1, cnt[1]=list2
#define LIST_OFF  (CNT_OFF + 64)                                // int list1 rows (<=65536)
#define LIST2_OFF (LIST_OFF + (size_t)NROW * 4)                 // int list2 rows (cap 4096)
#define CAND_OFF  (LIST2_OFF + (size_t)LIST2_CAP * 4)           // int2 (k2,k3) per row
#define ZPART_OFF (CAND_OFF + (size_t)NROW * 8)                 // float zpart[12288]
#define KEY_OFF   (ZPART_OFF + (size_t)NPART * 4)               // u64 keys (cap 4096)

static __device__ inline u16 f2bf(float x) {
    u32 u = __float_as_uint(x);
    u += 0x7fffu + ((u >> 16) & 1u);
    return (u16)(u >> 16);
}

typedef __attribute__((ext_vector_type(8))) short short8v;
typedef __attribute__((ext_vector_type(4))) float float4v;

static __device__ inline void gload16(const u16* g, u16* l) {
    __builtin_amdgcn_global_load_lds(
        (const __attribute__((address_space(1))) u32*)g,
        (__attribute__((address_space(3))) u32*)(uintptr_t)(void*)l,
        16, 0, 0);
}

#define LEXLT(av, ak, bv, bk) ((av) < (bv) || ((av) == (bv) && (ak) < (bk)))

// branchless sorted-insert of x into k1<=k2<=k3 (keep 3 smallest), 5 ops.
static __device__ inline void insk(int x, int& k1, int& k2, int& k3) {
    int t = max(k1, x);
    k1 = min(k1, x);
    int u = max(k2, t);
    k2 = min(k2, t);
    k3 = min(k3, u);
}

// ---------------- fused prep: ||e||^2 + e hi split (swizzled) + zero counters/loss + init keys ----------------
__global__ __launch_bounds__(256) void vq_prep(const float* __restrict__ e,
                                               u16* __restrict__ eh,
                                               float* __restrict__ ee, int* __restrict__ cnt,
                                               u64* __restrict__ keys,
                                               float* __restrict__ out)
{
    const int tid = threadIdx.x, bid = blockIdx.x;
    if (bid == 0 && tid == 0) { cnt[0] = 0; cnt[1] = 0; out[0] = 0.0f; }
    int lin = bid * 256 + tid;
    if (lin < LIST2_CAP) keys[lin] = ~0ull;
    if (bid < 4) {
        int k = bid * 256 + tid;
        const float* er = e + (size_t)k * D_DIM;
        double s = 0.0;
        for (int d = 0; d < D_DIM; ++d) { double ed = (double)er[d]; s = fma(ed, ed, s); }
        ee[k] = (float)s;
    }
    for (int t = lin; t < K_DIM * 96; t += 64 * 256) {
        int k = t / 96;
        int ch = t - k * 96;              // 8-elem chunk id
        const float* src = e + (size_t)k * D_DIM + ch * 8;
        u16 h[8];
        #pragma unroll
        for (int q = 0; q < 8; ++q) h[q] = f2bf(src[q]);
        int dst = (ch >> 3) * 64 + (((ch & 7) ^ (k & 7)) << 3);
        *(uint4*)(eh + (size_t)k * D_DIM + dst) = *(const uint4*)h;
    }
}

// ---------------- prep: z transpose -> bf16 zh (swizzled) + optional fp32 zt32 + z^2 partials ----------------
__global__ __launch_bounds__(256) void vq_prep_z(const float* __restrict__ z, u16* __restrict__ zh,
                                                 float* __restrict__ zt32, float* __restrict__ zpart)
{
    __shared__ u16 tmp[64][72];
    __shared__ float tmp32[64][66];
    __shared__ double lredd[4];
    int bi = blockIdx.x;
    int dg = bi % 12;
    int tg = (bi / 12) % 64;
    int b  = bi / (12 * 64);
    int tid = threadIdx.x;
    int tl4 = (tid & 15) * 4;
    int dl  = tid >> 4;
    double s = 0.0;
    #pragma unroll
    for (int p = 0; p < 4; ++p) {
        int d = dg * 64 + p * 16 + dl;
        const float* src = z + ((size_t)b * D_DIM + d) * T_DIM + tg * 64 + tl4;
        float4 v = *(const float4*)src;
        tmp[tl4 + 0][p * 16 + dl] = f2bf(v.x);
        tmp[tl4 + 1][p * 16 + dl] = f2bf(v.y);
        tmp[tl4 + 2][p * 16 + dl] = f2bf(v.z);
        tmp[tl4 + 3][p * 16 + dl] = f2bf(v.w);
        tmp32[tl4 + 0][p * 16 + dl] = v.x;
        tmp32[tl4 + 1][p * 16 + dl] = v.y;
        tmp32[tl4 + 2][p * 16 + dl] = v.z;
        tmp32[tl4 + 3][p * 16 + dl] = v.w;
        s = fma((double)v.x, (double)v.x, s);
        s = fma((double)v.y, (double)v.y, s);
        s = fma((double)v.z, (double)v.z, s);
        s = fma((double)v.w, (double)v.w, s);
    }
    #pragma unroll
    for (int m = 1; m < 64; m <<= 1) s += __shfl_xor(s, m);
    if ((tid & 63) == 0) lredd[tid >> 6] = s;
    __syncthreads();
    if (tid == 0) zpart[bi] = (float)(lredd[0] + lredd[1] + lredd[2] + lredd[3]);
    // zh write: lin = w*256 + tid -> 8 consecutive lanes cover one row's 8 chunks (128B window,
    // XOR-swizzle permutes within the window) -> fully coalesced 128B segments.
    #pragma unroll
    for (int w = 0; w < 2; ++w) {
        int lin = w * 256 + tid;          // 0..511 = 64 rows x 8 chunks
        int tl  = lin >> 3;
        int c   = lin & 7;
        size_t row_g = (size_t)b * T_DIM + tg * 64 + tl;
        int cs = c ^ ((int)row_g & 7);
        uint4 val = *(const uint4*)&tmp[tl][c * 8];
        *(uint4*)(zh + row_g * D_DIM + dg * 64 + cs * 8) = val;
    }
    if (zt32) {
        // zt32 write: lin = w*256 + tid -> 16 consecutive lanes cover one row's 64-col slice
        // (256B contiguous) -> fully coalesced.
        #pragma unroll
        for (int w = 0; w < 4; ++w) {
            int lin = w * 256 + tid;      // 0..1023 = 64 rows x 16 float4
            int tl = lin >> 4;
            int cq = lin & 15;
            size_t row_g = (size_t)b * T_DIM + tg * 64 + tl;
            float4 v;
            v.x = tmp32[tl][cq * 4 + 0];
            v.y = tmp32[tl][cq * 4 + 1];
            v.z = tmp32[tl][cq * 4 + 2];
            v.w = tmp32[tl][cq * 4 + 3];
            *(float4*)(zt32 + row_g * D_DIM + dg * 64 + cq * 4) = v;
        }
    }
}

// ---------------- main: bf16 MFMA scores (eh only), n0-PAIRED tiles, packed-key top-3 + routing + sc-sum ----------------
// Pairing amortizes the z-tile staging + barrier drain over 2 codebook tiles:
// barriers 192->96 per block, zt global re-reads 8x->4x. 128 acc + 128 arch = 256 unified regs
// -> hard 2 waves/SIMD (further pairing would spill; r14 lesson).
__global__ __launch_bounds__(256, 2) void vq_main_mfma(const u16* __restrict__ zh,
                                                       const u16* __restrict__ eh,
                                                       const float* __restrict__ ee_g,
                                                       float* __restrict__ out,
                                                       int* __restrict__ cnt,
                                                       int* __restrict__ list1,
                                                       int* __restrict__ list2,
                                                       int2* __restrict__ cand)
{
    __shared__ u16 zt[128 * 64];
    __shared__ u16 eht[2][128 * 64];
    __shared__ float eeS[K_DIM];              // ||e||^2 * 2^18
    __shared__ int pk3[128][2][3];
    __shared__ float scred[2];

    const int tid  = threadIdx.x;
    const int wid  = tid >> 6;
    const int lane = tid & 63;
    const int wm = wid >> 1, wn = wid & 1;
    const int l15 = lane & 15, l4 = lane >> 4;
    const int row_block = blockIdx.x * 128;

    for (int i = tid; i < K_DIM; i += 256) eeS[i] = ee_g[i] * 262144.0f;

    int kq1[16], kq2[16], kq3[16];
    #pragma unroll
    for (int i = 0; i < 16; ++i) { kq1[i] = 0x7fffffff; kq2[i] = 0x7fffffff; kq3[i] = 0x7fffffff; }

    const int r8 = lane >> 3;
    const int ch = lane & 7;

    for (int np = 0; np < 4; ++np) {
        float4v acc[2][4][4];
        #pragma unroll
        for (int u = 0; u < 2; ++u)
            #pragma unroll
            for (int mf = 0; mf < 4; ++mf)
                #pragma unroll
                for (int nf = 0; nf < 4; ++nf) acc[u][mf][nf] = (float4v)0.0f;

        for (int d0i = 0; d0i < 12; ++d0i) {
            const int d0 = d0i * 64;
            __syncthreads();
            #pragma unroll
            for (int q = 0; q < 4; ++q) {
                int lr = wid * 32 + q * 8;
                gload16(zh + (size_t)(row_block + lr + r8) * D_DIM + d0 + ch * 8, &zt[lr * 64]);
            }
            #pragma unroll
            for (int u = 0; u < 2; ++u)
                #pragma unroll
                for (int q = 0; q < 4; ++q) {
                    int lr = wid * 32 + q * 8;
                    gload16(eh + (size_t)(np * 256 + u * 128 + lr + r8) * D_DIM + d0 + ch * 8,
                            &eht[u][lr * 64]);
                }
            __syncthreads();

            #pragma unroll
            for (int s = 0; s < 2; ++s) {
                short8v a[4], bh4[2][4];
                #pragma unroll
                for (int mf = 0; mf < 4; ++mf) {
                    int r = wm * 64 + mf * 16 + l15;
                    int cs = (s * 4 + l4) ^ (r & 7);
                    a[mf] = *(const short8v*)&zt[r * 64 + cs * 8];
                }
                #pragma unroll
                for (int u = 0; u < 2; ++u)
                    #pragma unroll
                    for (int nf = 0; nf < 4; ++nf) {
                        int r = wn * 64 + nf * 16 + l15;
                        int cs = (s * 4 + l4) ^ (r & 7);
                        bh4[u][nf] = *(const short8v*)&eht[u][r * 64 + cs * 8];
                    }
                #pragma unroll
                for (int u = 0; u < 2; ++u)
                    #pragma unroll
                    for (int mf = 0; mf < 4; ++mf)
                        #pragma unroll
                        for (int nf = 0; nf < 4; ++nf)
                            acc[u][mf][nf] = __builtin_amdgcn_mfma_f32_16x16x32_bf16(a[mf], bh4[u][nf], acc[u][mf][nf], 0, 0, 0);
            }
        }

        // fold: key = ((int)((ee - 2*acc) * 2^18) << 10) + code ; keep 3 smallest per slot
        // (fold order u=0 then u=1 == ascending n0 -> identical keys to unpaired version)
        #pragma unroll
        for (int u = 0; u < 2; ++u)
            #pragma unroll
            for (int nf = 0; nf < 4; ++nf) {
                int kg = (np * 2 + u) * 128 + wn * 64 + nf * 16 + l15;
                float eev = eeS[kg];
                #pragma unroll
                for (int mf = 0; mf < 4; ++mf)
                    #pragma unroll
                    for (int rr = 0; rr < 4; ++rr) {
                        float sc2 = fmaf(acc[u][mf][nf][rr], -524288.0f, eev);   // sc * 2^18
                        int si = (int)sc2;
                        int key = (si << 10) + kg;
                        const int slot = mf * 4 + rr;
                        insk(key, kq1[slot], kq2[slot], kq3[slot]);
                    }
            }
    }

    // merge across the 16 lanes sharing l4 (masks 1,2,4,8)
    #pragma unroll
    for (int m = 1; m < 16; m <<= 1) {
        #pragma unroll
        for (int i = 0; i < 16; ++i) {
            int o1 = __shfl_xor(kq1[i], m);
            int o2 = __shfl_xor(kq2[i], m);
            int o3 = __shfl_xor(kq3[i], m);
            insk(o1, kq1[i], kq2[i], kq3[i]);
            insk(o2, kq1[i], kq2[i], kq3[i]);
            insk(o3, kq1[i], kq2[i], kq3[i]);
        }
    }

    // publish per-half top-3, merge halves, route
    if (l15 == 0) {
        #pragma unroll
        for (int mf = 0; mf < 4; ++mf)
            #pragma unroll
            for (int rr = 0; rr < 4; ++rr) {
                int slot = mf * 4 + rr;
                int rl = wm * 64 + mf * 16 + l4 * 4 + rr;   // 0..127
                pk3[rl][wn][0] = kq1[slot];
                pk3[rl][wn][1] = kq2[slot];
                pk3[rl][wn][2] = kq3[slot];
            }
    }
    __syncthreads();
    float scf = 0.0f;
    if (tid < 128) {
        int a1 = pk3[tid][0][0], a2 = pk3[tid][0][1], a3 = pk3[tid][0][2];
        insk(pk3[tid][1][0], a1, a2, a3);
        insk(pk3[tid][1][1], a1, a2, a3);
        insk(pk3[tid][1][2], a1, a2, a3);
        int s1 = a1 >> 10, s2 = a2 >> 10, s3 = a3 >> 10;   // arithmetic shift -> si
        int row = row_block + tid;
        out[IDX_OFF + row] = (float)(a1 & 1023);
        scf = (float)s1 * SC_SCALE;
        if (s3 - s1 < MARGIN_SI) {
            int p = atomicAdd(&cnt[1], 1);
            if (p < LIST2_CAP) list2[p] = row;
        } else if (s2 - s1 < MARGIN_SI) {
            int p = atomicAdd(&cnt[0], 1);
            list1[p] = row;
            cand[row] = make_int2(a2 & 1023, a3 & 1023);
        }
    }
    // sc-sum for loss (waves 2,3 contribute 0)
    #pragma unroll
    for (int m = 1; m < 64; m <<= 1) scf += __shfl_xor(scf, m);
    if (lane == 0 && wid < 2) scred[wid] = scf;
    __syncthreads();
    if (tid == 0) atomicAdd(out, (scred[0] + scred[1]) * INV_N);
}

// ---------------- fixup-lite: exact numpy-fp32 rescore of {k1,k2,k3} per flagged row ----------------
__global__ __launch_bounds__(256) void vq_fixup_lite(const float* __restrict__ z,
                                                     const float* __restrict__ zt32,
                                                     const float* __restrict__ e,
                                                     const float* __restrict__ ee,
                                                     float* __restrict__ out,
                                                     const int* __restrict__ list1,
                                                     const int* __restrict__ cnt,
                                                     const int2* __restrict__ cand)
{
    __shared__ float zr[16][776];
    __shared__ double afl[16];
    __shared__ int rowsL[16];
    __shared__ int candL[16][3];
    __shared__ float dqL[16][3];

    const int tid = threadIdx.x;
    int total = cnt[0];
    if (total > NROW) total = NROW;
    int ngroups = (total + 15) >> 4;

    for (int g = blockIdx.x; g < ngroups; g += gridDim.x) {
        int nr = total - g * 16; if (nr > 16) nr = 16;
        __syncthreads();
        if (tid < 16) {
            int row = list1[g * 16 + ((tid < nr) ? tid : 0)];
            rowsL[tid] = row;
            candL[tid][0] = (int)out[IDX_OFF + row];
            int2 cc = cand[row];
            candL[tid][1] = cc.x;
            candL[tid][2] = cc.y;
        }
        __syncthreads();
        if (zt32) {
            #pragma unroll
            for (int j = 0; j < 12; ++j) {
                int lin = tid + 256 * j;          // 0..3071 = 16 rows x 192 float4
                int r = lin / 192;
                int dq = (lin - r * 192) * 4;
                *(float4*)&zr[r][dq] = *(const float4*)(zt32 + (size_t)rowsL[r] * D_DIM + dq);
            }
        } else {
            int r = tid >> 4, sub = tid & 15;
            int row = rowsL[r];
            int b = row >> 12, t = row & 4095;
            const float* zp = z + (size_t)b * D_DIM * T_DIM + t;
            #pragma unroll 4
            for (int j = 0; j < 48; ++j) {
                int d = sub + 16 * j;
                zr[r][d] = zp[(size_t)d * T_DIM];
            }
        }
        __syncthreads();
        {   // A = fl32(fp64 sum z^2) (any assoc: grid-shift invariance)
            int r = tid >> 4, sub = tid & 15;
            double s = 0.0;
            for (int d = sub; d < D_DIM; d += 16) { double zd = (double)zr[r][d]; s = fma(zd, zd, s); }
            #pragma unroll
            for (int m = 1; m < 16; m <<= 1) s += __shfl_xor(s, m);
            if (sub == 0) afl[r] = s;
        }
        __syncthreads();
        if (tid < 96) {
            int c = tid >> 5;             // candidate 0..2
            int p = (tid >> 4) & 1;       // panel 0/1
            int r = tid & 15;             // row slot
            int kk = candL[r][c];
            const float* ep = e + (size_t)kk * D_DIM + p * 384;
            const float* zp = &zr[r][p * 384];
            float a0 = 0.0f;
            #pragma unroll 8
            for (int j = 0; j < 96; ++j) {
                float4 ev = *(const float4*)(ep + j * 4);
                float4 zv = *(const float4*)(zp + j * 4);
                a0 = fmaf(zv.x, ev.x, a0);
                a0 = fmaf(zv.y, ev.y, a0);
                a0 = fmaf(zv.z, ev.z, a0);
                a0 = fmaf(zv.w, ev.w, a0);
            }
            float other = __shfl_xor(a0, 16);
            if (p == 0) {
                float M  = a0 + other;                 // fl(S1+S2), OpenBLAS 384-panel split
                float t1 = (float)afl[r] + ee[kk];     // fl(A+E)
                dqL[r][c] = t1 - 2.0f * M;             // fl(fl(A+E) - 2M)
            }
        }
        __syncthreads();
        if (tid < nr) {
            float dv = dqL[tid][0]; int dk = candL[tid][0];
            #pragma unroll
            for (int c = 1; c < 3; ++c) {
                float v = dqL[tid][c]; int k2 = candL[tid][c];
                if (LEXLT(v, k2, dv, dk)) { dv = v; dk = k2; }
            }
            out[IDX_OFF + rowsL[tid]] = (float)dk;
        }
    }
}

// ---------------- fixup-full: exact 1024-code scan, sliced 8-ways across blocks ----------------
__global__ __launch_bounds__(256) void vq_fixup_full(const float* __restrict__ z,
                                                     const float* __restrict__ zt32,
                                                     const float* __restrict__ e,
                                                     const float* __restrict__ ee,
                                                     const int* __restrict__ list2,
                                                     const int* __restrict__ cnt,
                                                     u64* __restrict__ keys)
{
    __shared__ float zr[8][ZPAD];
    __shared__ double afl[8];
    __shared__ int rowsL[8];
    __shared__ float dvL[8][17];
    __shared__ int   dkL[8][17];

    const int tid = threadIdx.x;
    const int p = tid & 1;
    const int r = (tid >> 1) & 7;
    const int c = tid >> 4;
    int total = cnt[1];
    if (total > LIST2_CAP) total = LIST2_CAP;
    if (total == 0) return;
    int nchunk = (total + 7) >> 3;
    int ntasks = nchunk * 8;

    for (int task = blockIdx.x; task < ntasks; task += gridDim.x) {
        int cj = task >> 3;
        int slice = task & 7;
        int nr = total - cj * 8; if (nr > 8) nr = 8;
        __syncthreads();
        if (tid < 8) rowsL[tid] = list2[cj * 8 + ((tid < nr) ? tid : 0)];
        __syncthreads();
        if (zt32) {
            #pragma unroll
            for (int j = 0; j < 6; ++j) {
                int lin = tid + 256 * j;          // 0..1535 = 8 rows x 192 float4
                int r2 = lin / 192;
                int dq = (lin - r2 * 192) * 4;
                *(float4*)&zr[r2][dq] = *(const float4*)(zt32 + (size_t)rowsL[r2] * D_DIM + dq);
            }
        } else {
            int rs = tid >> 5, sub = tid & 31;
            int row = rowsL[rs];
            int b = row >> 12, t = row & 4095;
            const float* zp = z + (size_t)b * D_DIM * T_DIM + t;
            #pragma unroll 4
            for (int j = 0; j < 24; ++j) {
                int d = sub + 32 * j;
                zr[rs][d] = zp[(size_t)d * T_DIM];
            }
        }
        __syncthreads();
        {   // A = fl32(fp64 sum z^2)
            int rs = tid >> 5, sub = tid & 31;
            double s = 0.0;
            for (int d = sub; d < D_DIM; d += 32) { double zd = (double)zr[rs][d]; s = fma(zd, zd, s); }
            #pragma unroll
            for (int m = 1; m < 32; m <<= 1) s += __shfl_xor(s, m);
            if (sub == 0) afl[rs] = s;
        }
        __syncthreads();
        const float Af = (float)afl[r];
        const float* zp = &zr[r][p * 384];

        float bd = 3.4e38f;
        int   bkk = 0x7fffffff;

        #pragma unroll 2
        for (int g2 = 0; g2 < 8; ++g2) {
            int code = slice * 128 + g2 * 16 + c;
            const float* ep = e + (size_t)code * D_DIM + p * 384;
            float a0 = 0.0f;
            #pragma unroll 8
            for (int j = 0; j < 96; ++j) {
                float4 zv = *(const float4*)(zp + j * 4);
                float4 ev = *(const float4*)(ep + j * 4);
                a0 = fmaf(zv.x, ev.x, a0);
                a0 = fmaf(zv.y, ev.y, a0);
                a0 = fmaf(zv.z, ev.z, a0);
                a0 = fmaf(zv.w, ev.w, a0);
            }
            float other = __shfl_xor(a0, 1);
            if (p == 0) {
                float M  = a0 + other;            // fl(S1+S2), OpenBLAS 384-panel split
                float t1 = Af + ee[code];         // fl(A+E)
                float dq = t1 - 2.0f * M;         // fl(fl(A+E) - 2M)
                if (LEXLT(dq, code, bd, bkk)) { bd = dq; bkk = code; }
            }
        }

        if (p == 0) { dvL[r][c] = bd; dkL[r][c] = bkk; }
        __syncthreads();
        if (tid < 8 && tid < nr) {
            float v = dvL[tid][0]; int kk = dkL[tid][0];
            #pragma unroll
            for (int i = 1; i < 16; ++i) {
                float v2 = dvL[tid][i]; int k2 = dkL[tid][i];
                if (LEXLT(v2, k2, v, kk)) { v = v2; kk = k2; }
            }
            u64 key = ((u64)__float_as_uint(v) << 32) | (u64)(u32)kk;
            atomicMin(&keys[cj * 8 + tid], key);
        }
        __syncthreads();
    }
}

// ---------------- finish: loss (z^2 partials) + convert full-scan keys -> idx ----------------
__global__ __launch_bounds__(256) void vq_finish(float* __restrict__ out,
                                                 const int* __restrict__ list2,
                                                 const int* __restrict__ cnt,
                                                 const u64* __restrict__ keys,
                                                 const float* __restrict__ zpart)
{
    __shared__ double r[4];
    double s = 0.0;
    for (int i = threadIdx.x; i < NPART; i += 256) s += (double)zpart[i];
    #pragma unroll
    for (int m = 1; m < 64; m <<= 1) s += __shfl_xor(s, m);
    if ((threadIdx.x & 63) == 0) r[threadIdx.x >> 6] = s;
    __syncthreads();
    if (threadIdx.x == 0) atomicAdd(out, (float)((r[0] + r[1] + r[2] + r[3]) * (double)INV_N));

    int total = cnt[1];
    if (total > LIST2_CAP) total = LIST2_CAP;
    for (int i = threadIdx.x; i < total; i += 256) {
        out[IDX_OFF + list2[i]] = (float)(u32)(keys[i] & 0xffffffffu);
    }
}

// ---------------- gather z_q -> transposed write (loss already accumulated) ----------------
__global__ __launch_bounds__(256) void vq_out(const float* __restrict__ e,
                                              float* __restrict__ out)
{
    const int tid  = threadIdx.x;
    const int mIdx = blockIdx.x;
    const int b    = mIdx >> 5;
    const int t0   = (mIdx & 31) * 128;

    const int t  = tid & 127;
    const int ds = tid >> 7;
    const int gt = t0 + t;
    const int k  = (int)out[IDX_OFF + (size_t)b * T_DIM + gt];
    const float* er = e + (size_t)k * D_DIM;
    for (int d0 = ds * 4; d0 < D_DIM; d0 += 8) {
        float4 v = *(const float4*)(er + d0);
        float vv[4];
        *(float4*)vv = v;
        #pragma unroll
        for (int j = 0; j < 4; ++j) {
            size_t o = (size_t)(b * D_DIM + d0 + j) * T_DIM + gt;
            out[1 + o] = vv[j];
        }
    }
}

extern "C" void kernel_launch(void* const* d_in, const int* in_sizes, int n_in,
                              void* d_out, int out_size, void* d_ws, size_t ws_size,
                              hipStream_t stream) {
    const float* z = (const float*)d_in[0];
    const float* e = (const float*)d_in[1];
    float* out = (float*)d_out;
    char* ob = (char*)d_out;
    u16*   zh    = (u16*)(ob + ZH_OFF);
    u16*   eh    = (u16*)(ob + EH_OFF);
    float* eeg   = (float*)(ob + EE_OFF);
    int*   cntp  = (int*)(ob + CNT_OFF);
    int*   list1 = (int*)(ob + LIST_OFF);
    int*   list2 = (int*)(ob + LIST2_OFF);
    int2*  candp = (int2*)(ob + CAND_OFF);
    float* zpart = (float*)(ob + ZPART_OFF);
    u64*   keys  = (u64*)(ob + KEY_OFF);
    // fp32 transposed z lives in d_ws when it fits; else fall back to strided gathers
    float* zt32 = (ws_size >= (size_t)NROW * D_DIM * 4) ? (float*)d_ws : nullptr;
    (void)in_sizes; (void)n_in; (void)out_size;

    vq_prep<<<dim3(64), dim3(256), 0, stream>>>(e, eh, eeg, cntp, keys, out);
    vq_prep_z<<<dim3(NPART), dim3(256), 0, stream>>>(z, zh, zt32, zpart);
    vq_main_mfma<<<dim3(NROW / 128), dim3(256), 0, stream>>>(zh, eh, eeg, out, cntp, list1, list2, candp);
    vq_fixup_lite<<<dim3(512), dim3(256), 0, stream>>>(z, zt32, e, eeg, out, list1, cntp, candp);
    vq_fixup_full<<<dim3(512), dim3(256), 0, stream>>>(z, zt32, e, eeg, list2, cntp, keys);
    vq_finish<<<dim3(1), dim3(256), 0, stream>>>(out, list2, cntp, keys, zpart);
    vq_out<<<dim3(512), dim3(256), 0, stream>>>(e, out);
}

// Round 18
// 388.957 us; speedup vs baseline: 1.5273x; 1.1419x over previous
//
#include <hip/hip_runtime.h>

typedef unsigned short u16;
typedef unsigned int   u32;
typedef unsigned long long u64;

#define B_DIM 16
#define D_DIM 768
#define T_DIM 4096
#define K_DIM 1024
#define NROW  (B_DIM * T_DIM)   // 65536 rows (b*T + t)
#define NPART (16 * 12 * 64)    // prep_z grid = 12288

// out layout (float32): out[0]=loss; out[1 + (b*D+d)*T + t]=z_q_st; out[IDX_OFF + b*T + t]=idx
#define IDX_OFF (1 + (size_t)B_DIM * D_DIM * T_DIM)

#define MARGIN_SI 150           // 2G numpy slack (32 si) + ~12.8 sigma of eh-only score noise
#define SC_SCALE 3.814697265625e-06f   // 2^-18
#define INV_N 1.9868215e-8f            // 1/(16*768*4096)

#define LIST2_CAP 4096
#define ZPAD2 780               // shared zr row stride: 780%32=12 -> full's 8-row chain conflict-free

#define NB_LITE 384
#define NB_FULL 640

// ---- scratch carved out of d_out's z_q region (overwritten by vq_out at the end) ----
#define ZH_OFF    ((size_t)64)                                  // bf16 z, [row][768], pre-swizzled (96 MB)
#define EH_OFF    (ZH_OFF + (size_t)NROW * D_DIM * 2)           // bf16 e hi
#define EL_OFF    (EH_OFF + (size_t)K_DIM * D_DIM * 2)          // (unused; layout stability)
#define EE_OFF    (EL_OFF + (size_t)K_DIM * D_DIM * 2)          // fp32 ||e_k||^2
#define CNT_OFF   (EE_OFF + (size_t)K_DIM * 4)                  // int cnt[0]=list1, cnt[1]=list2
#define LIST_OFF  (CNT_OFF + 64)                                // int list1 rows (<=65536)
#define LIST2_OFF (LIST_OFF + (size_t)NROW * 4)                 // int list2 rows (cap 4096)
#define CAND_OFF  (LIST2_OFF + (size_t)LIST2_CAP * 4)           // int2 (k2,k3) per row
#define ZPART_OFF (CAND_OFF + (size_t)NROW * 8)                 // float zpart[12288]
#define KEY_OFF   (ZPART_OFF + (size_t)NPART * 4)               // u64 keys (cap 4096)

static __device__ inline u16 f2bf(float x) {
    u32 u = __float_as_uint(x);
    u += 0x7fffu + ((u >> 16) & 1u);
    return (u16)(u >> 16);
}

typedef __attribute__((ext_vector_type(8))) short short8v;
typedef __attribute__((ext_vector_type(4))) float float4v;

static __device__ inline void gload16(const u16* g, u16* l) {
    __builtin_amdgcn_global_load_lds(
        (const __attribute__((address_space(1))) u32*)g,
        (__attribute__((address_space(3))) u32*)(uintptr_t)(void*)l,
        16, 0, 0);
}

#define LEXLT(av, ak, bv, bk) ((av) < (bv) || ((av) == (bv) && (ak) < (bk)))

// branchless sorted-insert of x into k1<=k2<=k3 (keep 3 smallest), 5 ops.
static __device__ inline void insk(int x, int& k1, int& k2, int& k3) {
    int t = max(k1, x);
    k1 = min(k1, x);
    int u = max(k2, t);
    k2 = min(k2, t);
    k3 = min(k3, u);
}

// ---------------- fused prep: blocks 0..63 = e-prep (||e||^2, eh split, init); 64.. = z transpose ----------------
__global__ __launch_bounds__(256) void vq_prep_all(const float* __restrict__ e,
                                                   u16* __restrict__ eh,
                                                   float* __restrict__ ee, int* __restrict__ cnt,
                                                   u64* __restrict__ keys,
                                                   float* __restrict__ out,
                                                   const float* __restrict__ z, u16* __restrict__ zh,
                                                   float* __restrict__ zt32, float* __restrict__ zpart)
{
    __shared__ u16 tmp[64][72];
    __shared__ float tmp32[64][66];
    __shared__ double lredd[4];
    const int tid = threadIdx.x;

    if (blockIdx.x < 64) {
        const int bid = blockIdx.x;
        if (bid == 0 && tid == 0) { cnt[0] = 0; cnt[1] = 0; out[0] = 0.0f; }
        int lin = bid * 256 + tid;
        if (lin < LIST2_CAP) keys[lin] = ~0ull;
        if (bid < 4) {
            int k = bid * 256 + tid;
            const float* er = e + (size_t)k * D_DIM;
            double s = 0.0;
            for (int d = 0; d < D_DIM; ++d) { double ed = (double)er[d]; s = fma(ed, ed, s); }
            ee[k] = (float)s;
        }
        for (int t = lin; t < K_DIM * 96; t += 64 * 256) {
            int k = t / 96;
            int ch = t - k * 96;              // 8-elem chunk id
            const float* src = e + (size_t)k * D_DIM + ch * 8;
            u16 h[8];
            #pragma unroll
            for (int q = 0; q < 8; ++q) h[q] = f2bf(src[q]);
            int dst = (ch >> 3) * 64 + (((ch & 7) ^ (k & 7)) << 3);
            *(uint4*)(eh + (size_t)k * D_DIM + dst) = *(const uint4*)h;
        }
        return;
    }

    int bi = blockIdx.x - 64;
    int dg = bi % 12;
    int tg = (bi / 12) % 64;
    int b  = bi / (12 * 64);
    int tl4 = (tid & 15) * 4;
    int dl  = tid >> 4;
    double s = 0.0;
    #pragma unroll
    for (int p = 0; p < 4; ++p) {
        int d = dg * 64 + p * 16 + dl;
        const float* src = z + ((size_t)b * D_DIM + d) * T_DIM + tg * 64 + tl4;
        float4 v = *(const float4*)src;
        tmp[tl4 + 0][p * 16 + dl] = f2bf(v.x);
        tmp[tl4 + 1][p * 16 + dl] = f2bf(v.y);
        tmp[tl4 + 2][p * 16 + dl] = f2bf(v.z);
        tmp[tl4 + 3][p * 16 + dl] = f2bf(v.w);
        tmp32[tl4 + 0][p * 16 + dl] = v.x;
        tmp32[tl4 + 1][p * 16 + dl] = v.y;
        tmp32[tl4 + 2][p * 16 + dl] = v.z;
        tmp32[tl4 + 3][p * 16 + dl] = v.w;
        s = fma((double)v.x, (double)v.x, s);
        s = fma((double)v.y, (double)v.y, s);
        s = fma((double)v.z, (double)v.z, s);
        s = fma((double)v.w, (double)v.w, s);
    }
    #pragma unroll
    for (int m = 1; m < 64; m <<= 1) s += __shfl_xor(s, m);
    if ((tid & 63) == 0) lredd[tid >> 6] = s;
    __syncthreads();
    if (tid == 0) zpart[bi] = (float)(lredd[0] + lredd[1] + lredd[2] + lredd[3]);
    // zh write: lin = w*256 + tid -> fully coalesced 128B segments (swizzle permutes within window)
    #pragma unroll
    for (int w = 0; w < 2; ++w) {
        int lin = w * 256 + tid;          // 0..511 = 64 rows x 8 chunks
        int tl  = lin >> 3;
        int c   = lin & 7;
        size_t row_g = (size_t)b * T_DIM + tg * 64 + tl;
        int cs = c ^ ((int)row_g & 7);
        uint4 val = *(const uint4*)&tmp[tl][c * 8];
        *(uint4*)(zh + row_g * D_DIM + dg * 64 + cs * 8) = val;
    }
    if (zt32) {
        #pragma unroll
        for (int w = 0; w < 4; ++w) {
            int lin = w * 256 + tid;      // 0..1023 = 64 rows x 16 float4
            int tl = lin >> 4;
            int cq = lin & 15;
            size_t row_g = (size_t)b * T_DIM + tg * 64 + tl;
            float4 v;
            v.x = tmp32[tl][cq * 4 + 0];
            v.y = tmp32[tl][cq * 4 + 1];
            v.z = tmp32[tl][cq * 4 + 2];
            v.w = tmp32[tl][cq * 4 + 3];
            *(float4*)(zt32 + row_g * D_DIM + dg * 64 + cq * 4) = v;
        }
    }
}

// ---------------- main: bf16 MFMA scores (eh only), n0-PAIRED tiles, packed-key top-3 + routing + sc-sum ----------------
// Pairing amortizes the z-tile staging + barrier drain over 2 codebook tiles:
// barriers 192->96 per block. 128 acc + 128 arch = 256 unified regs -> hard 2 waves/SIMD.
__global__ __launch_bounds__(256, 2) void vq_main_mfma(const u16* __restrict__ zh,
                                                       const u16* __restrict__ eh,
                                                       const float* __restrict__ ee_g,
                                                       float* __restrict__ out,
                                                       int* __restrict__ cnt,
                                                       int* __restrict__ list1,
                                                       int* __restrict__ list2,
                                                       int2* __restrict__ cand)
{
    __shared__ u16 zt[128 * 64];
    __shared__ u16 eht[2][128 * 64];
    __shared__ float eeS[K_DIM];              // ||e||^2 * 2^18
    __shared__ int pk3[128][2][3];
    __shared__ float scred[2];

    const int tid  = threadIdx.x;
    const int wid  = tid >> 6;
    const int lane = tid & 63;
    const int wm = wid >> 1, wn = wid & 1;
    const int l15 = lane & 15, l4 = lane >> 4;
    const int row_block = blockIdx.x * 128;

    for (int i = tid; i < K_DIM; i += 256) eeS[i] = ee_g[i] * 262144.0f;

    int kq1[16], kq2[16], kq3[16];
    #pragma unroll
    for (int i = 0; i < 16; ++i) { kq1[i] = 0x7fffffff; kq2[i] = 0x7fffffff; kq3[i] = 0x7fffffff; }

    const int r8 = lane >> 3;
    const int ch = lane & 7;

    for (int np = 0; np < 4; ++np) {
        float4v acc[2][4][4];
        #pragma unroll
        for (int u = 0; u < 2; ++u)
            #pragma unroll
            for (int mf = 0; mf < 4; ++mf)
                #pragma unroll
                for (int nf = 0; nf < 4; ++nf) acc[u][mf][nf] = (float4v)0.0f;

        for (int d0i = 0; d0i < 12; ++d0i) {
            const int d0 = d0i * 64;
            __syncthreads();
            #pragma unroll
            for (int q = 0; q < 4; ++q) {
                int lr = wid * 32 + q * 8;
                gload16(zh + (size_t)(row_block + lr + r8) * D_DIM + d0 + ch * 8, &zt[lr * 64]);
            }
            #pragma unroll
            for (int u = 0; u < 2; ++u)
                #pragma unroll
                for (int q = 0; q < 4; ++q) {
                    int lr = wid * 32 + q * 8;
                    gload16(eh + (size_t)(np * 256 + u * 128 + lr + r8) * D_DIM + d0 + ch * 8,
                            &eht[u][lr * 64]);
                }
            __syncthreads();

            #pragma unroll
            for (int s = 0; s < 2; ++s) {
                short8v a[4], bh4[2][4];
                #pragma unroll
                for (int mf = 0; mf < 4; ++mf) {
                    int r = wm * 64 + mf * 16 + l15;
                    int cs = (s * 4 + l4) ^ (r & 7);
                    a[mf] = *(const short8v*)&zt[r * 64 + cs * 8];
                }
                #pragma unroll
                for (int u = 0; u < 2; ++u)
                    #pragma unroll
                    for (int nf = 0; nf < 4; ++nf) {
                        int r = wn * 64 + nf * 16 + l15;
                        int cs = (s * 4 + l4) ^ (r & 7);
                        bh4[u][nf] = *(const short8v*)&eht[u][r * 64 + cs * 8];
                    }
                #pragma unroll
                for (int u = 0; u < 2; ++u)
                    #pragma unroll
                    for (int mf = 0; mf < 4; ++mf)
                        #pragma unroll
                        for (int nf = 0; nf < 4; ++nf)
                            acc[u][mf][nf] = __builtin_amdgcn_mfma_f32_16x16x32_bf16(a[mf], bh4[u][nf], acc[u][mf][nf], 0, 0, 0);
            }
        }

        // fold: key = ((int)((ee - 2*acc) * 2^18) << 10) + code ; keep 3 smallest per slot
        #pragma unroll
        for (int u = 0; u < 2; ++u)
            #pragma unroll
            for (int nf = 0; nf < 4; ++nf) {
                int kg = (np * 2 + u) * 128 + wn * 64 + nf * 16 + l15;
                float eev = eeS[kg];
                #pragma unroll
                for (int mf = 0; mf < 4; ++mf)
                    #pragma unroll
                    for (int rr = 0; rr < 4; ++rr) {
                        float sc2 = fmaf(acc[u][mf][nf][rr], -524288.0f, eev);   // sc * 2^18
                        int si = (int)sc2;
                        int key = (si << 10) + kg;
                        const int slot = mf * 4 + rr;
                        insk(key, kq1[slot], kq2[slot], kq3[slot]);
                    }
            }
    }

    // merge across the 16 lanes sharing l4 (masks 1,2,4,8)
    #pragma unroll
    for (int m = 1; m < 16; m <<= 1) {
        #pragma unroll
        for (int i = 0; i < 16; ++i) {
            int o1 = __shfl_xor(kq1[i], m);
            int o2 = __shfl_xor(kq2[i], m);
            int o3 = __shfl_xor(kq3[i], m);
            insk(o1, kq1[i], kq2[i], kq3[i]);
            insk(o2, kq1[i], kq2[i], kq3[i]);
            insk(o3, kq1[i], kq2[i], kq3[i]);
        }
    }

    // publish per-half top-3, merge halves, route
    if (l15 == 0) {
        #pragma unroll
        for (int mf = 0; mf < 4; ++mf)
            #pragma unroll
            for (int rr = 0; rr < 4; ++rr) {
                int slot = mf * 4 + rr;
                int rl = wm * 64 + mf * 16 + l4 * 4 + rr;   // 0..127
                pk3[rl][wn][0] = kq1[slot];
                pk3[rl][wn][1] = kq2[slot];
                pk3[rl][wn][2] = kq3[slot];
            }
    }
    __syncthreads();
    float scf = 0.0f;
    if (tid < 128) {
        int a1 = pk3[tid][0][0], a2 = pk3[tid][0][1], a3 = pk3[tid][0][2];
        insk(pk3[tid][1][0], a1, a2, a3);
        insk(pk3[tid][1][1], a1, a2, a3);
        insk(pk3[tid][1][2], a1, a2, a3);
        int s1 = a1 >> 10, s2 = a2 >> 10, s3 = a3 >> 10;   // arithmetic shift -> si
        int row = row_block + tid;
        out[IDX_OFF + row] = (float)(a1 & 1023);
        scf = (float)s1 * SC_SCALE;
        if (s3 - s1 < MARGIN_SI) {
            int p = atomicAdd(&cnt[1], 1);
            if (p < LIST2_CAP) list2[p] = row;
        } else if (s2 - s1 < MARGIN_SI) {
            int p = atomicAdd(&cnt[0], 1);
            list1[p] = row;
            cand[row] = make_int2(a2 & 1023, a3 & 1023);
        }
    }
    // sc-sum for loss (waves 2,3 contribute 0)
    #pragma unroll
    for (int m = 1; m < 64; m <<= 1) scf += __shfl_xor(scf, m);
    if (lane == 0 && wid < 2) scred[wid] = scf;
    __syncthreads();
    if (tid == 0) atomicAdd(out, (scred[0] + scred[1]) * INV_N);
}

// ---------------- merged fixup: blocks 0..NB_LITE-1 = lite path; rest = full path (concurrent) ----------------
__global__ __launch_bounds__(256) void vq_fixup2(const float* __restrict__ z,
                                                 const float* __restrict__ zt32,
                                                 const float* __restrict__ e,
                                                 const float* __restrict__ ee,
                                                 float* __restrict__ out,
                                                 const int* __restrict__ list1,
                                                 const int* __restrict__ list2,
                                                 const int* __restrict__ cnt,
                                                 const int2* __restrict__ cand,
                                                 u64* __restrict__ keys)
{
    __shared__ float zr[16][ZPAD2];
    __shared__ double afl[16];
    __shared__ int rowsL[16];
    __shared__ int candL[16][3];
    __shared__ float dqL[16][3];
    __shared__ float dvL[8][17];
    __shared__ int   dkL[8][17];

    const int tid = threadIdx.x;

    if (blockIdx.x < NB_LITE) {
        // ---- lite: exact numpy-fp32 rescore of {k1,k2,k3} per flagged row ----
        int total = cnt[0];
        if (total > NROW) total = NROW;
        int ngroups = (total + 15) >> 4;

        for (int g = blockIdx.x; g < ngroups; g += NB_LITE) {
            int nr = total - g * 16; if (nr > 16) nr = 16;
            __syncthreads();
            if (tid < 16) {
                int row = list1[g * 16 + ((tid < nr) ? tid : 0)];
                rowsL[tid] = row;
                candL[tid][0] = (int)out[IDX_OFF + row];
                int2 cc = cand[row];
                candL[tid][1] = cc.x;
                candL[tid][2] = cc.y;
            }
            __syncthreads();
            if (zt32) {
                #pragma unroll
                for (int j = 0; j < 12; ++j) {
                    int lin = tid + 256 * j;          // 0..3071 = 16 rows x 192 float4
                    int r = lin / 192;
                    int dq = (lin - r * 192) * 4;
                    *(float4*)&zr[r][dq] = *(const float4*)(zt32 + (size_t)rowsL[r] * D_DIM + dq);
                }
            } else {
                int r = tid >> 4, sub = tid & 15;
                int row = rowsL[r];
                int b = row >> 12, t = row & 4095;
                const float* zp = z + (size_t)b * D_DIM * T_DIM + t;
                #pragma unroll 4
                for (int j = 0; j < 48; ++j) {
                    int d = sub + 16 * j;
                    zr[r][d] = zp[(size_t)d * T_DIM];
                }
            }
            __syncthreads();
            {   // A = fl32(fp64 sum z^2) (any assoc: grid-shift invariance)
                int r = tid >> 4, sub = tid & 15;
                double s = 0.0;
                for (int d = sub; d < D_DIM; d += 16) { double zd = (double)zr[r][d]; s = fma(zd, zd, s); }
                #pragma unroll
                for (int m = 1; m < 16; m <<= 1) s += __shfl_xor(s, m);
                if (sub == 0) afl[r] = s;
            }
            __syncthreads();
            if (tid < 96) {
                int c = tid >> 5;             // candidate 0..2
                int p = (tid >> 4) & 1;       // panel 0/1
                int r = tid & 15;             // row slot
                int kk = candL[r][c];
                const float* ep = e + (size_t)kk * D_DIM + p * 384;
                const float* zp = &zr[r][p * 384];
                float a0 = 0.0f;
                #pragma unroll 8
                for (int j = 0; j < 96; ++j) {
                    float4 ev = *(const float4*)(ep + j * 4);
                    float4 zv = *(const float4*)(zp + j * 4);
                    a0 = fmaf(zv.x, ev.x, a0);
                    a0 = fmaf(zv.y, ev.y, a0);
                    a0 = fmaf(zv.z, ev.z, a0);
                    a0 = fmaf(zv.w, ev.w, a0);
                }
                float other = __shfl_xor(a0, 16);
                if (p == 0) {
                    float M  = a0 + other;                 // fl(S1+S2), OpenBLAS 384-panel split
                    float t1 = (float)afl[r] + ee[kk];     // fl(A+E)
                    dqL[r][c] = t1 - 2.0f * M;             // fl(fl(A+E) - 2M)
                }
            }
            __syncthreads();
            if (tid < nr) {
                float dv = dqL[tid][0]; int dk = candL[tid][0];
                #pragma unroll
                for (int c = 1; c < 3; ++c) {
                    float v = dqL[tid][c]; int k2 = candL[tid][c];
                    if (LEXLT(v, k2, dv, dk)) { dv = v; dk = k2; }
                }
                out[IDX_OFF + rowsL[tid]] = (float)dk;
            }
        }
        return;
    }

    // ---- full: exact 1024-code scan, sliced 8-ways across blocks ----
    const int bid2 = blockIdx.x - NB_LITE;
    const int p = tid & 1;
    const int r = (tid >> 1) & 7;
    const int c = tid >> 4;
    int total = cnt[1];
    if (total > LIST2_CAP) total = LIST2_CAP;
    if (total == 0) return;
    int nchunk = (total + 7) >> 3;
    int ntasks = nchunk * 8;

    for (int task = bid2; task < ntasks; task += NB_FULL) {
        int cj = task >> 3;
        int slice = task & 7;
        int nr = total - cj * 8; if (nr > 8) nr = 8;
        __syncthreads();
        if (tid < 8) rowsL[tid] = list2[cj * 8 + ((tid < nr) ? tid : 0)];
        __syncthreads();
        if (zt32) {
            #pragma unroll
            for (int j = 0; j < 6; ++j) {
                int lin = tid + 256 * j;          // 0..1535 = 8 rows x 192 float4
                int r2 = lin / 192;
                int dq = (lin - r2 * 192) * 4;
                *(float4*)&zr[r2][dq] = *(const float4*)(zt32 + (size_t)rowsL[r2] * D_DIM + dq);
            }
        } else {
            int rs = tid >> 5, sub = tid & 31;
            int row = rowsL[rs];
            int b = row >> 12, t = row & 4095;
            const float* zp = z + (size_t)b * D_DIM * T_DIM + t;
            #pragma unroll 4
            for (int j = 0; j < 24; ++j) {
                int d = sub + 32 * j;
                zr[rs][d] = zp[(size_t)d * T_DIM];
            }
        }
        __syncthreads();
        {   // A = fl32(fp64 sum z^2)
            int rs = tid >> 5, sub = tid & 31;
            double s = 0.0;
            for (int d = sub; d < D_DIM; d += 32) { double zd = (double)zr[rs][d]; s = fma(zd, zd, s); }
            #pragma unroll
            for (int m = 1; m < 32; m <<= 1) s += __shfl_xor(s, m);
            if (sub == 0) afl[rs] = s;
        }
        __syncthreads();
        const float Af = (float)afl[r];
        const float* zp = &zr[r][p * 384];

        float bd = 3.4e38f;
        int   bkk = 0x7fffffff;

        #pragma unroll 2
        for (int g2 = 0; g2 < 8; ++g2) {
            int code = slice * 128 + g2 * 16 + c;
            const float* ep = e + (size_t)code * D_DIM + p * 384;
            float a0 = 0.0f;
            #pragma unroll 8
            for (int j = 0; j < 96; ++j) {
                float4 zv = *(const float4*)(zp + j * 4);
                float4 ev = *(const float4*)(ep + j * 4);
                a0 = fmaf(zv.x, ev.x, a0);
                a0 = fmaf(zv.y, ev.y, a0);
                a0 = fmaf(zv.z, ev.z, a0);
                a0 = fmaf(zv.w, ev.w, a0);
            }
            float other = __shfl_xor(a0, 1);
            if (p == 0) {
                float M  = a0 + other;            // fl(S1+S2), OpenBLAS 384-panel split
                float t1 = Af + ee[code];         // fl(A+E)
                float dq = t1 - 2.0f * M;         // fl(fl(A+E) - 2M)
                if (LEXLT(dq, code, bd, bkk)) { bd = dq; bkk = code; }
            }
        }

        if (p == 0) { dvL[r][c] = bd; dkL[r][c] = bkk; }
        __syncthreads();
        if (tid < 8 && tid < nr) {
            float v = dvL[tid][0]; int kk = dkL[tid][0];
            #pragma unroll
            for (int i = 1; i < 16; ++i) {
                float v2 = dvL[tid][i]; int k2 = dkL[tid][i];
                if (LEXLT(v2, k2, v, kk)) { v = v2; kk = k2; }
            }
            u64 key = ((u64)__float_as_uint(v) << 32) | (u64)(u32)kk;
            atomicMin(&keys[cj * 8 + tid], key);
        }
        __syncthreads();
    }
}

// ---------------- finish: loss (z^2 partials) + convert full-scan keys -> idx ----------------
__global__ __launch_bounds__(256) void vq_finish(float* __restrict__ out,
                                                 const int* __restrict__ list2,
                                                 const int* __restrict__ cnt,
                                                 const u64* __restrict__ keys,
                                                 const float* __restrict__ zpart)
{
    __shared__ double r[4];
    double s = 0.0;
    for (int i = threadIdx.x; i < NPART; i += 256) s += (double)zpart[i];
    #pragma unroll
    for (int m = 1; m < 64; m <<= 1) s += __shfl_xor(s, m);
    if ((threadIdx.x & 63) == 0) r[threadIdx.x >> 6] = s;
    __syncthreads();
    if (threadIdx.x == 0) atomicAdd(out, (float)((r[0] + r[1] + r[2] + r[3]) * (double)INV_N));

    int total = cnt[1];
    if (total > LIST2_CAP) total = LIST2_CAP;
    for (int i = threadIdx.x; i < total; i += 256) {
        out[IDX_OFF + list2[i]] = (float)(u32)(keys[i] & 0xffffffffu);
    }
}

// ---------------- gather z_q -> transposed write (loss already accumulated) ----------------
__global__ __launch_bounds__(256) void vq_out(const float* __restrict__ e,
                                              float* __restrict__ out)
{
    const int tid  = threadIdx.x;
    const int mIdx = blockIdx.x;
    const int b    = mIdx >> 5;
    const int t0   = (mIdx & 31) * 128;

    const int t  = tid & 127;
    const int ds = tid >> 7;
    const int gt = t0 + t;
    const int k  = (int)out[IDX_OFF + (size_t)b * T_DIM + gt];
    const float* er = e + (size_t)k * D_DIM;
    for (int d0 = ds * 4; d0 < D_DIM; d0 += 8) {
        float4 v = *(const float4*)(er + d0);
        float vv[4];
        *(float4*)vv = v;
        #pragma unroll
        for (int j = 0; j < 4; ++j) {
            size_t o = (size_t)(b * D_DIM + d0 + j) * T_DIM + gt;
            out[1 + o] = vv[j];
        }
    }
}

extern "C" void kernel_launch(void* const* d_in, const int* in_sizes, int n_in,
                              void* d_out, int out_size, void* d_ws, size_t ws_size,
                              hipStream_t stream) {
    const float* z = (const float*)d_in[0];
    const float* e = (const float*)d_in[1];
    float* out = (float*)d_out;
    char* ob = (char*)d_out;
    u16*   zh    = (u16*)(ob + ZH_OFF);
    u16*   eh    = (u16*)(ob + EH_OFF);
    float* eeg   = (float*)(ob + EE_OFF);
    int*   cntp  = (int*)(ob + CNT_OFF);
    int*   list1 = (int*)(ob + LIST_OFF);
    int*   list2 = (int*)(ob + LIST2_OFF);
    int2*  candp = (int2*)(ob + CAND_OFF);
    float* zpart = (float*)(ob + ZPART_OFF);
    u64*   keys  = (u64*)(ob + KEY_OFF);
    // fp32 transposed z lives in d_ws when it fits; else fall back to strided gathers
    float* zt32 = (ws_size >= (size_t)NROW * D_DIM * 4) ? (float*)d_ws : nullptr;
    (void)in_sizes; (void)n_in; (void)out_size;

    vq_prep_all<<<dim3(NPART + 64), dim3(256), 0, stream>>>(e, eh, eeg, cntp, keys, out, z, zh, zt32, zpart);
    vq_main_mfma<<<dim3(NROW / 128), dim3(256), 0, stream>>>(zh, eh, eeg, out, cntp, list1, list2, candp);
    vq_fixup2<<<dim3(NB_LITE + NB_FULL), dim3(256), 0, stream>>>(z, zt32, e, eeg, out, list1, list2, cntp, candp, keys);
    vq_finish<<<dim3(1), dim3(256), 0, stream>>>(out, list2, cntp, keys, zpart);
    vq_out<<<dim3(512), dim3(256), 0, stream>>>(e, out);
}